// Round 1
// baseline (752.790 us; speedup 1.0000x reference)
//
#include <hip/hip_runtime.h>
#include <math.h>

#define N_NODES 10000
#define B_SZ 4
#define D_DIM 128
#define SLOPE 0.01f
#define BN (B_SZ * N_NODES)

// ---------------- CSR build ----------------

__global__ __launch_bounds__(256) void init_kernel(int* deg, int* cursor, float* state_emb) {
    int i = blockIdx.x * 256 + threadIdx.x;
    if (i < N_NODES) { deg[i] = 0; cursor[i] = 0; }
    if (i < B_SZ * D_DIM) state_emb[i] = 0.f;
}

__global__ __launch_bounds__(256) void hist_kernel(const int* __restrict__ dst, int Etot, int* deg) {
    int e = blockIdx.x * 256 + threadIdx.x;
    if (e < Etot) atomicAdd(&deg[dst[e]], 1);
}

__global__ __launch_bounds__(1024) void scan_kernel(const int* __restrict__ deg, int* __restrict__ rowOff) {
    __shared__ int sm[1024];
    __shared__ int carrySh;
    int tid = threadIdx.x;
    if (tid == 0) { rowOff[0] = 0; carrySh = 0; }
    __syncthreads();
    for (int c0 = 0; c0 < N_NODES; c0 += 1024) {
        int i = c0 + tid;
        int v = (i < N_NODES) ? deg[i] : 0;
        sm[tid] = v;
        __syncthreads();
        for (int off = 1; off < 1024; off <<= 1) {
            int t = (tid >= off) ? sm[tid - off] : 0;
            __syncthreads();
            sm[tid] += t;
            __syncthreads();
        }
        int carry = carrySh;
        if (i < N_NODES) rowOff[i + 1] = carry + sm[tid];
        __syncthreads();
        if (tid == 1023) carrySh = carry + sm[1023];
        __syncthreads();
    }
}

__global__ __launch_bounds__(256) void scatter_kernel(const int* __restrict__ dst, int Etot,
                                                      const int* __restrict__ rowOff,
                                                      int* cursor, int* __restrict__ edgeLst) {
    int e = blockIdx.x * 256 + threadIdx.x;
    if (e < Etot) {
        int d = dst[e];
        int pos = rowOff[d] + atomicAdd(&cursor[d], 1);
        edgeLst[pos] = e;
    }
}

// ---------------- GAT layer kernels ----------------

// h = (x + state*Wns + bns) @ W ; a_src = h . attS ; a_dst = h . attD
// 32 rows (b,n pairs) per block, 256 threads: thread = (row 0..31, colgroup 0..7), 16 cols each.
__global__ __launch_bounds__(256) void gemm_att_kernel(
    const float* __restrict__ xin,   // layer0: strucEmb [N,D]; else X [B,N,D]
    int layer0,
    const float* __restrict__ state, // [B,N] flat (g = b*N + n)
    const float* __restrict__ W,     // [128,128] row-major (k, c)
    const float* __restrict__ attS, const float* __restrict__ attD,
    const float* __restrict__ Wns, const float* __restrict__ bns,
    float* __restrict__ Hout, float* __restrict__ aSrc, float* __restrict__ aDst)
{
    __shared__ float sX[32 * 128];
    __shared__ float sW[32 * 128];
    __shared__ float sAs[128], sAd[128];
    int tid = threadIdx.x;
    int g0 = blockIdx.x * 32;

    if (tid < 128) { sAs[tid] = attS[tid]; sAd[tid] = attD[tid]; }
    for (int i = tid; i < 32 * 128; i += 256) {
        int r = i >> 7, k = i & 127;
        int g = g0 + r;
        int b = g / N_NODES, n = g - b * N_NODES;
        float v = layer0 ? xin[n * 128 + k] : xin[(size_t)g * 128 + k];
        v += state[g] * Wns[k] + bns[k];
        sX[i] = v;
    }

    float acc[16];
#pragma unroll
    for (int j = 0; j < 16; j++) acc[j] = 0.f;
    int row = tid >> 3, cg = tid & 7;

    for (int kc = 0; kc < 4; kc++) {
        __syncthreads();
        for (int i = tid; i < 32 * 128; i += 256)
            sW[i] = W[kc * 32 * 128 + i];
        __syncthreads();
#pragma unroll
        for (int k = 0; k < 32; k++) {
            float xv = sX[row * 128 + kc * 32 + k];
#pragma unroll
            for (int j = 0; j < 16; j++)
                acc[j] += xv * sW[k * 128 + cg * 16 + j];
        }
    }

    int g = g0 + row;
    float4* Hp = (float4*)(Hout + (size_t)g * 128 + cg * 16);
#pragma unroll
    for (int j4 = 0; j4 < 4; j4++)
        Hp[j4] = make_float4(acc[j4 * 4], acc[j4 * 4 + 1], acc[j4 * 4 + 2], acc[j4 * 4 + 3]);

    float ps = 0.f, pd = 0.f;
#pragma unroll
    for (int j = 0; j < 16; j++) {
        ps += acc[j] * sAs[cg * 16 + j];
        pd += acc[j] * sAd[cg * 16 + j];
    }
    ps += __shfl_down(ps, 4, 8); ps += __shfl_down(ps, 2, 8); ps += __shfl_down(ps, 1, 8);
    pd += __shfl_down(pd, 4, 8); pd += __shfl_down(pd, 2, 8); pd += __shfl_down(pd, 1, 8);
    if (cg == 0) { aSrc[g] = ps; aDst[g] = pd; }
}

// Per-node softmax over incoming edges. 1 wave/node: lane = (edge 0..15)*4 + b.
__global__ __launch_bounds__(64) void softmax_kernel(
    const int* __restrict__ rowOff, const int* __restrict__ edgeLst,
    const int* __restrict__ srcArr,
    const float* __restrict__ aSrc, const float* __restrict__ aDst,
    float* __restrict__ alpha)
{
    int n = blockIdx.x;
    int start = rowOff[n], end = rowOff[n + 1];
    int lane = threadIdx.x;
    int el = lane >> 2, b = lane & 3;
    float adst = aDst[b * N_NODES + n];

    float m = -1e30f;
    for (int base = start; base < end; base += 16) {
        int idx = base + el;
        float ae = -1e30f;
        if (idx < end) {
            int sn = srcArr[edgeLst[idx]];
            float v = aSrc[b * N_NODES + sn] + adst;
            ae = v > 0.f ? v : SLOPE * v;
        }
        m = fmaxf(m, ae);
    }
    m = fmaxf(m, __shfl_xor(m, 4));
    m = fmaxf(m, __shfl_xor(m, 8));
    m = fmaxf(m, __shfl_xor(m, 16));
    m = fmaxf(m, __shfl_xor(m, 32));

    float s = 0.f;
    for (int base = start; base < end; base += 16) {
        int idx = base + el;
        if (idx < end) {
            int sn = srcArr[edgeLst[idx]];
            float v = aSrc[b * N_NODES + sn] + adst;
            float ae = v > 0.f ? v : SLOPE * v;
            s += __expf(ae - m);
        }
    }
    s += __shfl_xor(s, 4); s += __shfl_xor(s, 8); s += __shfl_xor(s, 16); s += __shfl_xor(s, 32);
    float inv = 1.f / s;

    for (int base = start; base < end; base += 16) {
        int idx = base + el;
        if (idx < end) {
            int sn = srcArr[edgeLst[idx]];
            float v = aSrc[b * N_NODES + sn] + adst;
            float ae = v > 0.f ? v : SLOPE * v;
            alpha[idx * 4 + b] = __expf(ae - m) * inv;
        }
    }
}

// X[b,n,:] = relu( sum_e alpha * H[b,src,:] + bias )
__global__ __launch_bounds__(128) void aggregate_kernel(
    const int* __restrict__ rowOff, const int* __restrict__ edgeLst,
    const int* __restrict__ srcArr,
    const float* __restrict__ alpha, const float* __restrict__ Hin,
    const float* __restrict__ bias, float* __restrict__ Xout)
{
    int n = blockIdx.x, b = blockIdx.y;
    int d = threadIdx.x;
    int start = rowOff[n], end = rowOff[n + 1];
    float acc = 0.f;
    for (int pos = start; pos < end; pos++) {
        int sn = srcArr[edgeLst[pos]];
        float al = alpha[pos * 4 + b];
        acc += al * Hin[((size_t)(b * N_NODES + sn)) * 128 + d];
    }
    float v = acc + bias[d];
    Xout[((size_t)(b * N_NODES + n)) * 128 + d] = v > 0.f ? v : 0.f;
}

// ---------------- head ----------------

__global__ __launch_bounds__(128) void sum_nodes_kernel(const float* __restrict__ X, float* state_emb) {
    int cx = blockIdx.x, b = blockIdx.y, d = threadIdx.x;
    int n0 = cx * 157, n1 = n0 + 157;
    if (n1 > N_NODES) n1 = N_NODES;
    float acc = 0.f;
    for (int n = n0; n < n1; n++) acc += X[((size_t)(b * N_NODES + n)) * 128 + d];
    atomicAdd(&state_emb[b * 128 + d], acc);
}

// c1[b] = sum_d relu(state_emb[b]@W1 + b1)[d] * W3[d]
__global__ __launch_bounds__(512) void beta_state_kernel(
    const float* __restrict__ state_emb, const float* __restrict__ W1,
    const float* __restrict__ b1, const float* __restrict__ W3, float* c1)
{
    __shared__ float sm[512];
    int tid = threadIdx.x;
    int b = tid >> 7, d = tid & 127;
    float acc = b1[d];
    for (int k = 0; k < 128; k++) acc += state_emb[b * 128 + k] * W1[k * 128 + d];
    float v = acc > 0.f ? acc : 0.f;
    sm[tid] = v * W3[d];
    __syncthreads();
    for (int s = 64; s > 0; s >>= 1) {
        if (d < s) sm[tid] += sm[tid + s];
        __syncthreads();
    }
    if (d == 0) c1[b] = sm[tid];
}

// out[g] = c1[b] + b3 + sum_d relu( (X[g]@W2)[d] + b2[d] ) * W3[128+d]
__global__ __launch_bounds__(256) void final_kernel(
    const float* __restrict__ X, const float* __restrict__ W2,
    const float* __restrict__ b2, const float* __restrict__ W3,
    const float* __restrict__ b3, const float* __restrict__ c1,
    float* __restrict__ out)
{
    __shared__ float sX[32 * 128];
    __shared__ float sW[32 * 128];
    int tid = threadIdx.x;
    int g0 = blockIdx.x * 32;

    for (int i = tid; i < 32 * 128; i += 256)
        sX[i] = X[(size_t)g0 * 128 + i];

    float acc[16];
#pragma unroll
    for (int j = 0; j < 16; j++) acc[j] = 0.f;
    int row = tid >> 3, cg = tid & 7;

    for (int kc = 0; kc < 4; kc++) {
        __syncthreads();
        for (int i = tid; i < 32 * 128; i += 256)
            sW[i] = W2[kc * 32 * 128 + i];
        __syncthreads();
#pragma unroll
        for (int k = 0; k < 32; k++) {
            float xv = sX[row * 128 + kc * 32 + k];
#pragma unroll
            for (int j = 0; j < 16; j++)
                acc[j] += xv * sW[k * 128 + cg * 16 + j];
        }
    }

    float p = 0.f;
#pragma unroll
    for (int j = 0; j < 16; j++) {
        int c = cg * 16 + j;
        float v = acc[j] + b2[c];
        v = v > 0.f ? v : 0.f;
        p += v * W3[128 + c];
    }
    p += __shfl_down(p, 4, 8); p += __shfl_down(p, 2, 8); p += __shfl_down(p, 1, 8);
    if (cg == 0) {
        int g = g0 + row;
        int b = g / N_NODES;
        out[g] = p + c1[b] + b3[0];
    }
}

// ---------------- launch ----------------

extern "C" void kernel_launch(void* const* d_in, const int* in_sizes, int n_in,
                              void* d_out, int out_size, void* d_ws, size_t ws_size,
                              hipStream_t stream) {
    const float* state    = (const float*)d_in[0];   // [B,N]
    const float* strucEmb = (const float*)d_in[1];   // [N,D]
    const int*   edge_idx = (const int*)d_in[2];     // [2,Etot]
    const float* gat_W    = (const float*)d_in[3];   // [3,128,128]
    const float* gat_aS   = (const float*)d_in[4];   // [3,1,128]
    const float* gat_aD   = (const float*)d_in[5];   // [3,1,128]
    const float* gat_Wns  = (const float*)d_in[6];   // [3,1,128]
    const float* gat_bns  = (const float*)d_in[7];   // [3,128]
    const float* gat_bias = (const float*)d_in[8];   // [3,128]
    const float* W1 = (const float*)d_in[9];
    const float* b1 = (const float*)d_in[10];
    const float* W2 = (const float*)d_in[11];
    const float* b2 = (const float*)d_in[12];
    const float* W3 = (const float*)d_in[13];
    const float* b3 = (const float*)d_in[14];
    float* out = (float*)d_out;

    int Etot = in_sizes[2] / 2;
    const int* srcArr = edge_idx;
    const int* dstArr = edge_idx + Etot;

    float* ws = (float*)d_ws;
    float* X         = ws;                 // 5,120,000 f
    float* Hbuf      = ws + 5120000;       // 5,120,000 f
    float* aSrc      = ws + 10240000;      // 40,000 f
    float* aDst      = ws + 10280000;      // 40,000 f
    float* alpha     = ws + 10320000;      // 680,000 f
    float* state_emb = ws + 11000000;      // 512 f
    float* c1        = ws + 11000512;      // 4 f
    int*   iws       = (int*)(ws + 11000516);
    int*   rowOff    = iws;                // N+1
    int*   deg       = iws + 10001;        // N
    int*   cursor    = deg + 10000;        // N
    int*   edgeLst   = cursor + 10000;     // Etot

    // CSR build (every call; graph-capture safe)
    init_kernel<<<40, 256, 0, stream>>>(deg, cursor, state_emb);
    hist_kernel<<<(Etot + 255) / 256, 256, 0, stream>>>(dstArr, Etot, deg);
    scan_kernel<<<1, 1024, 0, stream>>>(deg, rowOff);
    scatter_kernel<<<(Etot + 255) / 256, 256, 0, stream>>>(dstArr, Etot, rowOff, cursor, edgeLst);

    for (int l = 0; l < 3; l++) {
        gemm_att_kernel<<<BN / 32, 256, 0, stream>>>(
            l == 0 ? strucEmb : X, l == 0 ? 1 : 0, state,
            gat_W + (size_t)l * 128 * 128, gat_aS + l * 128, gat_aD + l * 128,
            gat_Wns + l * 128, gat_bns + l * 128, Hbuf, aSrc, aDst);
        softmax_kernel<<<N_NODES, 64, 0, stream>>>(rowOff, edgeLst, srcArr, aSrc, aDst, alpha);
        aggregate_kernel<<<dim3(N_NODES, B_SZ), 128, 0, stream>>>(
            rowOff, edgeLst, srcArr, alpha, Hbuf, gat_bias + l * 128, X);
    }

    sum_nodes_kernel<<<dim3(64, B_SZ), 128, 0, stream>>>(X, state_emb);
    beta_state_kernel<<<1, 512, 0, stream>>>(state_emb, W1, b1, W3, c1);
    final_kernel<<<BN / 32, 256, 0, stream>>>(X, W2, b2, W3, b3, c1, out);
}

// Round 3
// 404.298 us; speedup vs baseline: 1.8620x; 1.8620x over previous
//
#include <hip/hip_runtime.h>
#include <math.h>

#define N_NODES 10000
#define B_SZ 4
#define SLOPE 0.01f
#define BN (B_SZ * N_NODES)
#define PADK 136   // bf16 elems per LDS A-row (272B: 16B-aligned, bank-friendly)
#define PADC 129   // fp32 elems per LDS C-row

typedef __attribute__((ext_vector_type(8))) short short8;
typedef __attribute__((ext_vector_type(4))) short short4v;
typedef __attribute__((ext_vector_type(4))) float float4v;

__device__ __forceinline__ unsigned short f2bf(float f) {
    unsigned u = __builtin_bit_cast(unsigned, f);
    u += 0x7fffu + ((u >> 16) & 1u);   // round-to-nearest-even
    return (unsigned short)(u >> 16);
}
__device__ __forceinline__ float bf2f(unsigned short s) {
    unsigned u = ((unsigned)s) << 16;
    return __builtin_bit_cast(float, u);
}

// ---------------- CSR build ----------------

__global__ __launch_bounds__(256) void init_kernel(int* deg, int* cursor, float* state_emb) {
    int i = blockIdx.x * 256 + threadIdx.x;
    if (i < N_NODES) { deg[i] = 0; cursor[i] = 0; }
    if (i < B_SZ * 128) state_emb[i] = 0.f;
}

__global__ __launch_bounds__(256) void hist_kernel(const int* __restrict__ dst, int Etot, int* deg) {
    int e = blockIdx.x * 256 + threadIdx.x;
    if (e < Etot) atomicAdd(&deg[dst[e]], 1);
}

__global__ __launch_bounds__(1024) void scan_kernel(const int* __restrict__ deg, int* __restrict__ rowOff) {
    __shared__ int sm[1024];
    __shared__ int carrySh;
    int tid = threadIdx.x;
    if (tid == 0) { rowOff[0] = 0; carrySh = 0; }
    __syncthreads();
    for (int c0 = 0; c0 < N_NODES; c0 += 1024) {
        int i = c0 + tid;
        int v = (i < N_NODES) ? deg[i] : 0;
        sm[tid] = v;
        __syncthreads();
        for (int off = 1; off < 1024; off <<= 1) {
            int t = (tid >= off) ? sm[tid - off] : 0;
            __syncthreads();
            sm[tid] += t;
            __syncthreads();
        }
        int carry = carrySh;
        if (i < N_NODES) rowOff[i + 1] = carry + sm[tid];
        __syncthreads();
        if (tid == 1023) carrySh = carry + sm[1023];
        __syncthreads();
    }
}

__global__ __launch_bounds__(256) void scatter_kernel(const int* __restrict__ dst, int Etot,
                                                      const int* __restrict__ rowOff,
                                                      int* cursor, int* __restrict__ edgeLst) {
    int e = blockIdx.x * 256 + threadIdx.x;
    if (e < Etot) {
        int d = dst[e];
        int pos = rowOff[d] + atomicAdd(&cursor[d], 1);
        edgeLst[pos] = e;
    }
}

// ---------------- weight preprocessing: W[k][c] -> WT hi/lo bf16 [c][k] ----------------

__global__ __launch_bounds__(256) void wconv_kernel(const float* __restrict__ gatW,
                                                    const float* __restrict__ W2,
                                                    unsigned short* __restrict__ whi,
                                                    unsigned short* __restrict__ wlo) {
    int w = blockIdx.y;
    int i = blockIdx.x * 256 + threadIdx.x;   // 0..16383
    int k = i >> 7, c = i & 127;
    const float* src = (w < 3) ? (gatW + (size_t)w * 16384) : W2;
    float v = src[k * 128 + c];
    unsigned short h = f2bf(v);
    whi[w * 16384 + c * 128 + k] = h;
    wlo[w * 16384 + c * 128 + k] = f2bf(v - bf2f(h));
}

// ---------------- MFMA GEMM (GAT layer): H = (x + state*Wns + bns) @ W ; att dots ----------------
// block: 64 rows (g' = n*4+b node-major) x 128 cols; 256 threads = 4 waves, wave w -> cols w*32..+31

__global__ __launch_bounds__(256) void gemm_att_mfma(
    const float* __restrict__ xin, int layer0,
    const float* __restrict__ state,
    const unsigned short* __restrict__ WThi, const unsigned short* __restrict__ WTlo,
    const float* __restrict__ attS, const float* __restrict__ attD,
    const float* __restrict__ Wns, const float* __restrict__ bns,
    float* __restrict__ Hout, float* __restrict__ aSrcP, float* __restrict__ aDstP)
{
    __shared__ __align__(16) char smem[64 * PADK * 2 * 2];  // 34816 B; reused as sC (33024 B)
    unsigned short* sAh = (unsigned short*)smem;
    unsigned short* sAl = sAh + 64 * PADK;
    float* sC = (float*)smem;
    __shared__ float sWns[128], sBns[128], sAs[128], sAd[128];

    int tid = threadIdx.x;
    int g0 = blockIdx.x * 64;
    int w = tid >> 6, lane = tid & 63;
    int quad = lane >> 4, mcol = lane & 15;

    if (tid < 128) {
        sWns[tid] = Wns[tid]; sBns[tid] = bns[tid];
        sAs[tid] = attS[tid]; sAd[tid] = attD[tid];
    }

    // B fragments (held in registers for the whole kernel)
    short8 Bh[4][2], Bl[4][2];
#pragma unroll
    for (int kc = 0; kc < 4; kc++)
#pragma unroll
        for (int nt = 0; nt < 2; nt++) {
            int col = w * 32 + nt * 16 + mcol;
            Bh[kc][nt] = *(const short8*)(WThi + col * 128 + kc * 32 + quad * 8);
            Bl[kc][nt] = *(const short8*)(WTlo + col * 128 + kc * 32 + quad * 8);
        }

    __syncthreads();   // sWns/sBns ready

    // stage A (fp32 -> bf16 hi/lo split) into LDS
    for (int i4 = tid; i4 < 64 * 32; i4 += 256) {
        int r = i4 >> 5, k4 = (i4 & 31) << 2;
        int g = g0 + r, n = g >> 2, b = g & 3;
        const float* src = layer0 ? (xin + (size_t)n * 128 + k4) : (xin + (size_t)g * 128 + k4);
        float4 v = *(const float4*)src;
        float st = state[b * N_NODES + n];
        float x0 = v.x + st * sWns[k4]     + sBns[k4];
        float x1 = v.y + st * sWns[k4 + 1] + sBns[k4 + 1];
        float x2 = v.z + st * sWns[k4 + 2] + sBns[k4 + 2];
        float x3 = v.w + st * sWns[k4 + 3] + sBns[k4 + 3];
        unsigned short h0 = f2bf(x0), h1 = f2bf(x1), h2 = f2bf(x2), h3 = f2bf(x3);
        short4v hv = { (short)h0, (short)h1, (short)h2, (short)h3 };
        short4v lv = { (short)f2bf(x0 - bf2f(h0)), (short)f2bf(x1 - bf2f(h1)),
                       (short)f2bf(x2 - bf2f(h2)), (short)f2bf(x3 - bf2f(h3)) };
        *(short4v*)(sAh + r * PADK + k4) = hv;
        *(short4v*)(sAl + r * PADK + k4) = lv;
    }
    __syncthreads();

    float4v acc[4][2];
#pragma unroll
    for (int mt = 0; mt < 4; mt++)
#pragma unroll
        for (int nt = 0; nt < 2; nt++) acc[mt][nt] = (float4v){0.f, 0.f, 0.f, 0.f};

#pragma unroll
    for (int kc = 0; kc < 4; kc++) {
#pragma unroll
        for (int mt = 0; mt < 4; mt++) {
            short8 ah = *(const short8*)(sAh + (mt * 16 + mcol) * PADK + kc * 32 + quad * 8);
            short8 al = *(const short8*)(sAl + (mt * 16 + mcol) * PADK + kc * 32 + quad * 8);
#pragma unroll
            for (int nt = 0; nt < 2; nt++) {
                acc[mt][nt] = __builtin_amdgcn_mfma_f32_16x16x32_bf16(ah, Bh[kc][nt], acc[mt][nt], 0, 0, 0);
                acc[mt][nt] = __builtin_amdgcn_mfma_f32_16x16x32_bf16(al, Bh[kc][nt], acc[mt][nt], 0, 0, 0);
                acc[mt][nt] = __builtin_amdgcn_mfma_f32_16x16x32_bf16(ah, Bl[kc][nt], acc[mt][nt], 0, 0, 0);
            }
        }
    }

    __syncthreads();   // A-tiles fully consumed; reuse smem as C buffer
#pragma unroll
    for (int mt = 0; mt < 4; mt++)
#pragma unroll
        for (int nt = 0; nt < 2; nt++)
#pragma unroll
            for (int reg = 0; reg < 4; reg++) {
                int row = mt * 16 + quad * 4 + reg;   // C/D: col=lane&15, row=quad*4+reg
                int col = w * 32 + nt * 16 + mcol;
                sC[row * PADC + col] = acc[mt][nt][reg];
            }
    __syncthreads();

    // H write (coalesced) from LDS
    for (int i = tid; i < 64 * 128; i += 256) {
        int r = i >> 7, c = i & 127;
        Hout[(size_t)(g0 + r) * 128 + c] = sC[r * PADC + c];
    }
    // attention dots: 4 threads per row, 32 cols each
    int row = tid >> 2, q = tid & 3;
    float ps = 0.f, pd = 0.f;
#pragma unroll
    for (int j = 0; j < 32; j++) {
        float v2 = sC[row * PADC + q * 32 + j];
        ps += v2 * sAs[q * 32 + j];
        pd += v2 * sAd[q * 32 + j];
    }
    ps += __shfl_down(ps, 2, 4); ps += __shfl_down(ps, 1, 4);
    pd += __shfl_down(pd, 2, 4); pd += __shfl_down(pd, 1, 4);
    if (q == 0) { aSrcP[g0 + row] = ps; aDstP[g0 + row] = pd; }
}

// ---------------- fused softmax + aggregate: one block per node, all 4 batches ----------------
// wave b handles batch b; lanes t=0..63 cooperate on edges / feature dims.

__global__ __launch_bounds__(256) void sm_agg_kernel(
    const int* __restrict__ rowOff, const int* __restrict__ edgeLst,
    const int* __restrict__ srcArr,
    const float* __restrict__ aSrcP, const float* __restrict__ aDstP,
    const float* __restrict__ H,    // [n*4+b][128] fp32
    const float* __restrict__ bias, float* __restrict__ Xout)  // node-major
{
    __shared__ int sSrc[64];
    __shared__ float sAl[64 * 4];
    int n = blockIdx.x;
    int start = rowOff[n], end = rowOff[n + 1];
    int tid = threadIdx.x;
    int b = tid >> 6, t = tid & 63;
    float adst = aDstP[n * 4 + b];

    // pass 1: max
    float m = -1e30f;
    for (int i = start + t; i < end; i += 64) {
        int sn = srcArr[edgeLst[i]];
        float v = aSrcP[sn * 4 + b] + adst;
        m = fmaxf(m, v > 0.f ? v : SLOPE * v);
    }
    m = fmaxf(m, __shfl_xor(m, 1));  m = fmaxf(m, __shfl_xor(m, 2));
    m = fmaxf(m, __shfl_xor(m, 4));  m = fmaxf(m, __shfl_xor(m, 8));
    m = fmaxf(m, __shfl_xor(m, 16)); m = fmaxf(m, __shfl_xor(m, 32));

    // pass 2: sum of exp
    float s = 0.f;
    for (int i = start + t; i < end; i += 64) {
        int sn = srcArr[edgeLst[i]];
        float v = aSrcP[sn * 4 + b] + adst;
        float ae = v > 0.f ? v : SLOPE * v;
        s += __expf(ae - m);
    }
    s += __shfl_xor(s, 1);  s += __shfl_xor(s, 2);  s += __shfl_xor(s, 4);
    s += __shfl_xor(s, 8);  s += __shfl_xor(s, 16); s += __shfl_xor(s, 32);
    float inv = 1.f / s;

    // pass 3: alpha into LDS (chunks of 64), then gather-accumulate
    float2 acc = make_float2(0.f, 0.f);
    const float2* H2 = (const float2*)H;
    for (int c0 = start; c0 < end; c0 += 64) {
        int cnt = min(64, end - c0);
        if (t < cnt) {
            int e = edgeLst[c0 + t];
            int sn = srcArr[e];
            if (b == 0) sSrc[t] = sn;
            float v = aSrcP[sn * 4 + b] + adst;
            float ae = v > 0.f ? v : SLOPE * v;
            sAl[t * 4 + b] = __expf(ae - m) * inv;
        }
        __syncthreads();
        int j = 0;
        for (; j + 4 <= cnt; j += 4) {
            int s0 = sSrc[j], s1 = sSrc[j + 1], s2 = sSrc[j + 2], s3 = sSrc[j + 3];
            float a0 = sAl[j * 4 + b], a1 = sAl[(j + 1) * 4 + b];
            float a2 = sAl[(j + 2) * 4 + b], a3 = sAl[(j + 3) * 4 + b];
            float2 h0 = H2[(size_t)(s0 * 4 + b) * 64 + t];
            float2 h1 = H2[(size_t)(s1 * 4 + b) * 64 + t];
            float2 h2 = H2[(size_t)(s2 * 4 + b) * 64 + t];
            float2 h3 = H2[(size_t)(s3 * 4 + b) * 64 + t];
            acc.x += a0 * h0.x + a1 * h1.x + a2 * h2.x + a3 * h3.x;
            acc.y += a0 * h0.y + a1 * h1.y + a2 * h2.y + a3 * h3.y;
        }
        for (; j < cnt; j++) {
            int s0 = sSrc[j];
            float a0 = sAl[j * 4 + b];
            float2 h0 = H2[(size_t)(s0 * 4 + b) * 64 + t];
            acc.x += a0 * h0.x;
            acc.y += a0 * h0.y;
        }
        __syncthreads();
    }
    float ox = acc.x + bias[2 * t];
    float oy = acc.y + bias[2 * t + 1];
    ((float2*)Xout)[(size_t)(n * 4 + b) * 64 + t] = make_float2(ox > 0.f ? ox : 0.f, oy > 0.f ? oy : 0.f);
}

// ---------------- head ----------------

__global__ __launch_bounds__(128) void sum_nodes_kernel(const float* __restrict__ X, float* state_emb) {
    int cx = blockIdx.x, b = blockIdx.y, d = threadIdx.x;
    int n0 = cx * 157, n1 = n0 + 157;
    if (n1 > N_NODES) n1 = N_NODES;
    float acc = 0.f;
    for (int n = n0; n < n1; n++) acc += X[(size_t)(n * 4 + b) * 128 + d];
    atomicAdd(&state_emb[b * 128 + d], acc);
}

__global__ __launch_bounds__(512) void beta_state_kernel(
    const float* __restrict__ state_emb, const float* __restrict__ W1,
    const float* __restrict__ b1, const float* __restrict__ W3, float* c1)
{
    __shared__ float sm[512];
    int tid = threadIdx.x;
    int b = tid >> 7, d = tid & 127;
    float acc = b1[d];
    for (int k = 0; k < 128; k++) acc += state_emb[b * 128 + k] * W1[k * 128 + d];
    float v = acc > 0.f ? acc : 0.f;
    sm[tid] = v * W3[d];
    __syncthreads();
    for (int s = 64; s > 0; s >>= 1) {
        if (d < s) sm[tid] += sm[tid + s];
        __syncthreads();
    }
    if (d == 0) c1[b] = sm[tid];
}

// ---------------- final: out = relu(X@W2 + b2).W3[128:] + c1[b] + b3 ----------------

__global__ __launch_bounds__(256) void final_mfma(
    const float* __restrict__ X,
    const unsigned short* __restrict__ WThi, const unsigned short* __restrict__ WTlo,
    const float* __restrict__ b2, const float* __restrict__ W3,
    const float* __restrict__ b3, const float* __restrict__ c1,
    float* __restrict__ out)
{
    __shared__ __align__(16) char smem[64 * PADK * 2 * 2];
    unsigned short* sAh = (unsigned short*)smem;
    unsigned short* sAl = sAh + 64 * PADK;
    float* sC = (float*)smem;
    __shared__ float sB2[128], sW3[128];

    int tid = threadIdx.x;
    int g0 = blockIdx.x * 64;
    int w = tid >> 6, lane = tid & 63;
    int quad = lane >> 4, mcol = lane & 15;

    if (tid < 128) { sB2[tid] = b2[tid]; sW3[tid] = W3[128 + tid]; }

    short8 Bh[4][2], Bl[4][2];
#pragma unroll
    for (int kc = 0; kc < 4; kc++)
#pragma unroll
        for (int nt = 0; nt < 2; nt++) {
            int col = w * 32 + nt * 16 + mcol;
            Bh[kc][nt] = *(const short8*)(WThi + col * 128 + kc * 32 + quad * 8);
            Bl[kc][nt] = *(const short8*)(WTlo + col * 128 + kc * 32 + quad * 8);
        }

    for (int i4 = tid; i4 < 64 * 32; i4 += 256) {
        int r = i4 >> 5, k4 = (i4 & 31) << 2;
        int g = g0 + r;
        float4 v = *(const float4*)(X + (size_t)g * 128 + k4);
        unsigned short h0 = f2bf(v.x), h1 = f2bf(v.y), h2 = f2bf(v.z), h3 = f2bf(v.w);
        short4v hv = { (short)h0, (short)h1, (short)h2, (short)h3 };
        short4v lv = { (short)f2bf(v.x - bf2f(h0)), (short)f2bf(v.y - bf2f(h1)),
                       (short)f2bf(v.z - bf2f(h2)), (short)f2bf(v.w - bf2f(h3)) };
        *(short4v*)(sAh + r * PADK + k4) = hv;
        *(short4v*)(sAl + r * PADK + k4) = lv;
    }
    __syncthreads();

    float4v acc[4][2];
#pragma unroll
    for (int mt = 0; mt < 4; mt++)
#pragma unroll
        for (int nt = 0; nt < 2; nt++) acc[mt][nt] = (float4v){0.f, 0.f, 0.f, 0.f};

#pragma unroll
    for (int kc = 0; kc < 4; kc++) {
#pragma unroll
        for (int mt = 0; mt < 4; mt++) {
            short8 ah = *(const short8*)(sAh + (mt * 16 + mcol) * PADK + kc * 32 + quad * 8);
            short8 al = *(const short8*)(sAl + (mt * 16 + mcol) * PADK + kc * 32 + quad * 8);
#pragma unroll
            for (int nt = 0; nt < 2; nt++) {
                acc[mt][nt] = __builtin_amdgcn_mfma_f32_16x16x32_bf16(ah, Bh[kc][nt], acc[mt][nt], 0, 0, 0);
                acc[mt][nt] = __builtin_amdgcn_mfma_f32_16x16x32_bf16(al, Bh[kc][nt], acc[mt][nt], 0, 0, 0);
                acc[mt][nt] = __builtin_amdgcn_mfma_f32_16x16x32_bf16(ah, Bl[kc][nt], acc[mt][nt], 0, 0, 0);
            }
        }
    }

    __syncthreads();
#pragma unroll
    for (int mt = 0; mt < 4; mt++)
#pragma unroll
        for (int nt = 0; nt < 2; nt++)
#pragma unroll
            for (int reg = 0; reg < 4; reg++) {
                int row = mt * 16 + quad * 4 + reg;
                int col = w * 32 + nt * 16 + mcol;
                sC[row * PADC + col] = acc[mt][nt][reg];
            }
    __syncthreads();

    int row = tid >> 2, q = tid & 3;
    float p = 0.f;
#pragma unroll
    for (int j = 0; j < 32; j++) {
        int c = q * 32 + j;
        float v = sC[row * PADC + c] + sB2[c];
        v = v > 0.f ? v : 0.f;
        p += v * sW3[c];
    }
    p += __shfl_down(p, 2, 4); p += __shfl_down(p, 1, 4);
    if (q == 0) {
        int g = g0 + row;
        out[(g & 3) * N_NODES + (g >> 2)] = p + c1[g & 3] + b3[0];
    }
}

// ---------------- launch ----------------

extern "C" void kernel_launch(void* const* d_in, const int* in_sizes, int n_in,
                              void* d_out, int out_size, void* d_ws, size_t ws_size,
                              hipStream_t stream) {
    const float* state    = (const float*)d_in[0];   // [B,N]
    const float* strucEmb = (const float*)d_in[1];   // [N,128]
    const int*   edge_idx = (const int*)d_in[2];     // [2,Etot]
    const float* gat_W    = (const float*)d_in[3];   // [3,128,128]
    const float* gat_aS   = (const float*)d_in[4];
    const float* gat_aD   = (const float*)d_in[5];
    const float* gat_Wns  = (const float*)d_in[6];
    const float* gat_bns  = (const float*)d_in[7];
    const float* gat_bias = (const float*)d_in[8];
    const float* W1 = (const float*)d_in[9];
    const float* b1 = (const float*)d_in[10];
    const float* W2 = (const float*)d_in[11];
    const float* b2 = (const float*)d_in[12];
    const float* W3 = (const float*)d_in[13];
    const float* b3 = (const float*)d_in[14];
    float* out = (float*)d_out;

    int Etot = in_sizes[2] / 2;
    const int* srcArr = edge_idx;
    const int* dstArr = edge_idx + Etot;

    float* ws = (float*)d_ws;
    float* X         = ws;                   // 5,120,000 f (node-major [n*4+b][128])
    float* Hbuf      = ws + 5120000;         // 5,120,000 f (node-major)
    float* aSrcP     = ws + 10240000;        // 40,000 f  ([n*4+b])
    float* aDstP     = ws + 10280000;        // 40,000 f
    float* state_emb = ws + 10320000;        // 512 f
    float* c1        = ws + 10320512;        // 4 f
    unsigned short* whi = (unsigned short*)(ws + 10320516);  // 4*16384 ushorts = 32768 f
    unsigned short* wlo = whi + 4 * 16384;                   // 4*16384 ushorts = 32768 f
    // FIX (round 2 bug): skip BOTH whi and wlo = 65536 floats' worth, not 32768.
    int*   iws       = (int*)(ws + 10320516 + 65536);
    int*   rowOff    = iws;                  // N+1
    int*   deg       = iws + 10001;
    int*   cursor    = deg + 10000;
    int*   edgeLst   = cursor + 10000;       // Etot

    // weight preprocessing + CSR build (every call; graph-capture safe)
    wconv_kernel<<<dim3(64, 4), 256, 0, stream>>>(gat_W, W2, whi, wlo);
    init_kernel<<<40, 256, 0, stream>>>(deg, cursor, state_emb);
    hist_kernel<<<(Etot + 255) / 256, 256, 0, stream>>>(dstArr, Etot, deg);
    scan_kernel<<<1, 1024, 0, stream>>>(deg, rowOff);
    scatter_kernel<<<(Etot + 255) / 256, 256, 0, stream>>>(dstArr, Etot, rowOff, cursor, edgeLst);

    for (int l = 0; l < 3; l++) {
        gemm_att_mfma<<<BN / 64, 256, 0, stream>>>(
            l == 0 ? strucEmb : X, l == 0 ? 1 : 0, state,
            whi + (size_t)l * 16384, wlo + (size_t)l * 16384,
            gat_aS + l * 128, gat_aD + l * 128,
            gat_Wns + l * 128, gat_bns + l * 128, Hbuf, aSrcP, aDstP);
        sm_agg_kernel<<<N_NODES, 256, 0, stream>>>(
            rowOff, edgeLst, srcArr, aSrcP, aDstP, Hbuf, gat_bias + l * 128, X);
    }

    sum_nodes_kernel<<<dim3(64, B_SZ), 128, 0, stream>>>(X, state_emb);
    beta_state_kernel<<<1, 512, 0, stream>>>(state_emb, W1, b1, W3, c1);
    final_mfma<<<BN / 64, 256, 0, stream>>>(X, whi + 3 * 16384, wlo + 3 * 16384,
                                            b2, W3, b3, c1, out);
}

// Round 5
// 350.217 us; speedup vs baseline: 2.1495x; 1.1544x over previous
//
#include <hip/hip_runtime.h>
#include <math.h>

#define N_NODES 10000
#define B_SZ 4
#define SLOPE 0.01f
#define BN (B_SZ * N_NODES)
#define PADK 136   // bf16 elems per LDS A-row (272B: 16B-aligned, bank-friendly)

typedef __attribute__((ext_vector_type(8))) short short8;
typedef __attribute__((ext_vector_type(4))) short short4v;
typedef __attribute__((ext_vector_type(4))) float float4v;

__device__ __forceinline__ unsigned short f2bf(float f) {
    unsigned u = __builtin_bit_cast(unsigned, f);
    u += 0x7fffu + ((u >> 16) & 1u);   // round-to-nearest-even
    return (unsigned short)(u >> 16);
}
__device__ __forceinline__ float bf2f(unsigned short s) {
    unsigned u = ((unsigned)s) << 16;
    return __builtin_bit_cast(float, u);
}

// ---------------- CSR build ----------------

__global__ __launch_bounds__(256) void init_kernel(int* deg, int* cursor, float* state_emb) {
    int i = blockIdx.x * 256 + threadIdx.x;
    if (i < N_NODES) { deg[i] = 0; cursor[i] = 0; }
    if (i < B_SZ * 128) state_emb[i] = 0.f;
}

__global__ __launch_bounds__(256) void hist_kernel(const int* __restrict__ dst, int Etot, int* deg) {
    int e = blockIdx.x * 256 + threadIdx.x;
    if (e < Etot) atomicAdd(&deg[dst[e]], 1);
}

// 1024 threads, 10 elems/thread serial + wave shfl scan + wavesum scan. 2 barriers.
__global__ __launch_bounds__(1024) void scan_kernel(const int* __restrict__ deg, int* __restrict__ rowOff) {
    __shared__ int wsum[16];
    int tid = threadIdx.x;
    int lane = tid & 63, wid = tid >> 6;
    int base = tid * 10;
    int v[10]; int tot = 0;
#pragma unroll
    for (int j = 0; j < 10; j++) {
        int idx = base + j;
        int d = (idx < N_NODES) ? deg[idx] : 0;
        tot += d; v[j] = tot;
    }
    int incl = tot;
    for (int off = 1; off < 64; off <<= 1) {
        int t = __shfl_up(incl, off, 64);
        if (lane >= off) incl += t;
    }
    if (lane == 63) wsum[wid] = incl;
    __syncthreads();
    if (wid == 0) {
        int wv = (lane < 16) ? wsum[lane] : 0;
        for (int off = 1; off < 16; off <<= 1) {
            int t = __shfl_up(wv, off, 64);
            if (lane >= off) wv += t;
        }
        if (lane < 16) wsum[lane] = wv;
    }
    __syncthreads();
    int waveoff = (wid > 0) ? wsum[wid - 1] : 0;
    int excl = waveoff + incl - tot;
    if (tid == 0) rowOff[0] = 0;
#pragma unroll
    for (int j = 0; j < 10; j++) {
        int idx = base + j;
        if (idx < N_NODES) rowOff[idx + 1] = excl + v[j];
    }
}

__global__ __launch_bounds__(256) void scatter_kernel(const int* __restrict__ dst, int Etot,
                                                      const int* __restrict__ rowOff,
                                                      int* cursor, int* __restrict__ edgeLst) {
    int e = blockIdx.x * 256 + threadIdx.x;
    if (e < Etot) {
        int d = dst[e];
        int pos = rowOff[d] + atomicAdd(&cursor[d], 1);
        edgeLst[pos] = e;
    }
}

// ---------------- weight preprocessing: W[k][c] -> WT hi/lo bf16 [c][k] ----------------

__global__ __launch_bounds__(256) void wconv_kernel(const float* __restrict__ gatW,
                                                    const float* __restrict__ W2,
                                                    unsigned short* __restrict__ whi,
                                                    unsigned short* __restrict__ wlo) {
    int w = blockIdx.y;
    int i = blockIdx.x * 256 + threadIdx.x;   // 0..16383
    int k = i >> 7, c = i & 127;
    const float* src = (w < 3) ? (gatW + (size_t)w * 16384) : W2;
    float v = src[k * 128 + c];
    unsigned short h = f2bf(v);
    whi[w * 16384 + c * 128 + k] = h;
    wlo[w * 16384 + c * 128 + k] = f2bf(v - bf2f(h));
}

// ---------------- MFMA GEMM (GAT layer): H(bf16) = (x + state*Wns + bns) @ W ; att dots ----------------
// block: 64 rows (g = n*4+b node-major) x 128 cols; 256 threads = 4 waves, wave w -> cols w*32..+31

__global__ __launch_bounds__(256) void gemm_att_mfma(
    const float* __restrict__ xin, int layer0,
    const float* __restrict__ state,
    const unsigned short* __restrict__ WThi, const unsigned short* __restrict__ WTlo,
    const float* __restrict__ attS, const float* __restrict__ attD,
    const float* __restrict__ Wns, const float* __restrict__ bns,
    unsigned short* __restrict__ Hout, float* __restrict__ aSrcP, float* __restrict__ aDstP)
{
    __shared__ __align__(16) char smem[64 * PADK * 2 * 2];  // sAh+sAl 34816B; reused as sCus (17408B)
    unsigned short* sAh = (unsigned short*)smem;
    unsigned short* sAl = sAh + 64 * PADK;
    unsigned short* sCus = (unsigned short*)smem;
    __shared__ float sWns[128], sBns[128], sAs[128], sAd[128];
    __shared__ float sPart[64 * 4 * 2];   // [row][wave][ps/pd]

    int tid = threadIdx.x;
    int g0 = blockIdx.x * 64;
    int w = tid >> 6, lane = tid & 63;
    int quad = lane >> 4, mcol = lane & 15;

    if (tid < 128) {
        sWns[tid] = Wns[tid]; sBns[tid] = bns[tid];
        sAs[tid] = attS[tid]; sAd[tid] = attD[tid];
    }

    // B fragments (registers, whole kernel)
    short8 Bh[4][2], Bl[4][2];
#pragma unroll
    for (int kc = 0; kc < 4; kc++)
#pragma unroll
        for (int nt = 0; nt < 2; nt++) {
            int col = w * 32 + nt * 16 + mcol;
            Bh[kc][nt] = *(const short8*)(WThi + col * 128 + kc * 32 + quad * 8);
            Bl[kc][nt] = *(const short8*)(WTlo + col * 128 + kc * 32 + quad * 8);
        }

    __syncthreads();   // sWns/sBns ready

    // stage A (fp32 -> bf16 hi/lo split) into LDS
    for (int i4 = tid; i4 < 64 * 32; i4 += 256) {
        int r = i4 >> 5, k4 = (i4 & 31) << 2;
        int g = g0 + r, n = g >> 2, b = g & 3;
        const float* src = layer0 ? (xin + (size_t)n * 128 + k4) : (xin + (size_t)g * 128 + k4);
        float4 v = *(const float4*)src;
        float st = state[b * N_NODES + n];
        float x0 = v.x + st * sWns[k4]     + sBns[k4];
        float x1 = v.y + st * sWns[k4 + 1] + sBns[k4 + 1];
        float x2 = v.z + st * sWns[k4 + 2] + sBns[k4 + 2];
        float x3 = v.w + st * sWns[k4 + 3] + sBns[k4 + 3];
        unsigned short h0 = f2bf(x0), h1 = f2bf(x1), h2 = f2bf(x2), h3 = f2bf(x3);
        short4v hv = { (short)h0, (short)h1, (short)h2, (short)h3 };
        short4v lv = { (short)f2bf(x0 - bf2f(h0)), (short)f2bf(x1 - bf2f(h1)),
                       (short)f2bf(x2 - bf2f(h2)), (short)f2bf(x3 - bf2f(h3)) };
        *(short4v*)(sAh + r * PADK + k4) = hv;
        *(short4v*)(sAl + r * PADK + k4) = lv;
    }
    __syncthreads();

    float4v acc[4][2];
#pragma unroll
    for (int mt = 0; mt < 4; mt++)
#pragma unroll
        for (int nt = 0; nt < 2; nt++) acc[mt][nt] = (float4v){0.f, 0.f, 0.f, 0.f};

#pragma unroll
    for (int kc = 0; kc < 4; kc++) {
#pragma unroll
        for (int mt = 0; mt < 4; mt++) {
            short8 ah = *(const short8*)(sAh + (mt * 16 + mcol) * PADK + kc * 32 + quad * 8);
            short8 al = *(const short8*)(sAl + (mt * 16 + mcol) * PADK + kc * 32 + quad * 8);
#pragma unroll
            for (int nt = 0; nt < 2; nt++) {
                acc[mt][nt] = __builtin_amdgcn_mfma_f32_16x16x32_bf16(ah, Bh[kc][nt], acc[mt][nt], 0, 0, 0);
                acc[mt][nt] = __builtin_amdgcn_mfma_f32_16x16x32_bf16(al, Bh[kc][nt], acc[mt][nt], 0, 0, 0);
                acc[mt][nt] = __builtin_amdgcn_mfma_f32_16x16x32_bf16(ah, Bl[kc][nt], acc[mt][nt], 0, 0, 0);
            }
        }
    }

    __syncthreads();   // A-tiles consumed; reuse smem as bf16 C buffer

    // epilogue: bf16 C into LDS + register dots
    float pp[16], pd[16];
#pragma unroll
    for (int r16 = 0; r16 < 16; r16++) { pp[r16] = 0.f; pd[r16] = 0.f; }
#pragma unroll
    for (int mt = 0; mt < 4; mt++)
#pragma unroll
        for (int nt = 0; nt < 2; nt++)
#pragma unroll
            for (int reg = 0; reg < 4; reg++) {
                int row = mt * 16 + quad * 4 + reg;   // C/D: col=lane&15, row=quad*4+reg
                int col = w * 32 + nt * 16 + mcol;
                float v = acc[mt][nt][reg];
                sCus[row * PADK + col] = f2bf(v);
                pp[mt * 4 + reg] += v * sAs[col];
                pd[mt * 4 + reg] += v * sAd[col];
            }
#pragma unroll
    for (int off = 1; off < 16; off <<= 1)
#pragma unroll
        for (int r16 = 0; r16 < 16; r16++) {
            pp[r16] += __shfl_xor(pp[r16], off);
            pd[r16] += __shfl_xor(pd[r16], off);
        }
    if (mcol == 0) {
#pragma unroll
        for (int r16 = 0; r16 < 16; r16++) {
            int row = (r16 >> 2) * 16 + quad * 4 + (r16 & 3);
            sPart[row * 8 + w * 2 + 0] = pp[r16];
            sPart[row * 8 + w * 2 + 1] = pd[r16];
        }
    }
    __syncthreads();

    // H write (coalesced bf16) from LDS.
    // FIX (round-4 NaN bug): uint4 = 16B = 8 ushorts, c8 in 0..15, offset c8*8.
    // (Round 4 used uint2 [4 ushorts] with offset c8*8, c8 0..31 -> strided past
    //  row end, holes in H, and OOB write past Hb into aSrcP -> NaN.)
    for (int i = tid; i < 64 * 16; i += 256) {
        int r = i >> 4, c8 = i & 15;
        uint4 u = *(uint4*)(sCus + r * PADK + c8 * 8);
        *(uint4*)(Hout + (size_t)(g0 + r) * 128 + c8 * 8) = u;
    }
    if (tid < 64) {
        float s0 = sPart[tid * 8] + sPart[tid * 8 + 2] + sPart[tid * 8 + 4] + sPart[tid * 8 + 6];
        float s1 = sPart[tid * 8 + 1] + sPart[tid * 8 + 3] + sPart[tid * 8 + 5] + sPart[tid * 8 + 7];
        aSrcP[g0 + tid] = s0;
        aDstP[g0 + tid] = s1;
    }
}

// ---------------- fused softmax + aggregate: one block per node, all 4 batches ----------------
// wave b handles batch b; lanes t=0..63 cooperate on edges / feature dims. H is bf16.

__global__ __launch_bounds__(256) void sm_agg_kernel(
    const int* __restrict__ rowOff, const int* __restrict__ edgeLst,
    const int* __restrict__ srcArr,
    const float* __restrict__ aSrcP, const float* __restrict__ aDstP,
    const unsigned short* __restrict__ H,    // [n*4+b][128] bf16
    const float* __restrict__ bias, float* __restrict__ Xout)  // node-major fp32
{
    __shared__ int sSrc[64];
    __shared__ float sAl[64 * 4];
    int n = blockIdx.x;
    int start = rowOff[n], end = rowOff[n + 1];
    int tid = threadIdx.x;
    int b = tid >> 6, t = tid & 63;
    float adst = aDstP[n * 4 + b];

    // pass 1: max
    float m = -1e30f;
    for (int i = start + t; i < end; i += 64) {
        int sn = srcArr[edgeLst[i]];
        float v = aSrcP[sn * 4 + b] + adst;
        m = fmaxf(m, v > 0.f ? v : SLOPE * v);
    }
    m = fmaxf(m, __shfl_xor(m, 1));  m = fmaxf(m, __shfl_xor(m, 2));
    m = fmaxf(m, __shfl_xor(m, 4));  m = fmaxf(m, __shfl_xor(m, 8));
    m = fmaxf(m, __shfl_xor(m, 16)); m = fmaxf(m, __shfl_xor(m, 32));

    // pass 2: sum of exp
    float s = 0.f;
    for (int i = start + t; i < end; i += 64) {
        int sn = srcArr[edgeLst[i]];
        float v = aSrcP[sn * 4 + b] + adst;
        float ae = v > 0.f ? v : SLOPE * v;
        s += __expf(ae - m);
    }
    s += __shfl_xor(s, 1);  s += __shfl_xor(s, 2);  s += __shfl_xor(s, 4);
    s += __shfl_xor(s, 8);  s += __shfl_xor(s, 16); s += __shfl_xor(s, 32);
    float inv = 1.f / s;

    // pass 3: alpha into LDS (chunks of 64), then bf16 gather-accumulate
    float accx = 0.f, accy = 0.f;
    const unsigned int* Hu = (const unsigned int*)H;  // 2 bf16 per uint
    for (int c0 = start; c0 < end; c0 += 64) {
        int cnt = min(64, end - c0);
        if (t < cnt) {
            int e = edgeLst[c0 + t];
            int sn = srcArr[e];
            if (b == 0) sSrc[t] = sn;
            float v = aSrcP[sn * 4 + b] + adst;
            float ae = v > 0.f ? v : SLOPE * v;
            sAl[t * 4 + b] = __expf(ae - m) * inv;
        }
        __syncthreads();
        int j = 0;
        for (; j + 4 <= cnt; j += 4) {
            int s0 = sSrc[j], s1 = sSrc[j + 1], s2 = sSrc[j + 2], s3 = sSrc[j + 3];
            float a0 = sAl[j * 4 + b], a1 = sAl[(j + 1) * 4 + b];
            float a2 = sAl[(j + 2) * 4 + b], a3 = sAl[(j + 3) * 4 + b];
            unsigned int h0 = Hu[(size_t)(s0 * 4 + b) * 64 + t];
            unsigned int h1 = Hu[(size_t)(s1 * 4 + b) * 64 + t];
            unsigned int h2 = Hu[(size_t)(s2 * 4 + b) * 64 + t];
            unsigned int h3 = Hu[(size_t)(s3 * 4 + b) * 64 + t];
            accx += a0 * __builtin_bit_cast(float, h0 << 16) + a1 * __builtin_bit_cast(float, h1 << 16)
                  + a2 * __builtin_bit_cast(float, h2 << 16) + a3 * __builtin_bit_cast(float, h3 << 16);
            accy += a0 * __builtin_bit_cast(float, h0 & 0xffff0000u) + a1 * __builtin_bit_cast(float, h1 & 0xffff0000u)
                  + a2 * __builtin_bit_cast(float, h2 & 0xffff0000u) + a3 * __builtin_bit_cast(float, h3 & 0xffff0000u);
        }
        for (; j < cnt; j++) {
            int s0 = sSrc[j];
            float a0 = sAl[j * 4 + b];
            unsigned int h0 = Hu[(size_t)(s0 * 4 + b) * 64 + t];
            accx += a0 * __builtin_bit_cast(float, h0 << 16);
            accy += a0 * __builtin_bit_cast(float, h0 & 0xffff0000u);
        }
        __syncthreads();
    }
    float ox = accx + bias[2 * t];
    float oy = accy + bias[2 * t + 1];
    ((float2*)Xout)[(size_t)(n * 4 + b) * 64 + t] = make_float2(ox > 0.f ? ox : 0.f, oy > 0.f ? oy : 0.f);
}

// ---------------- head ----------------

__global__ __launch_bounds__(128) void sum_nodes_kernel(const float* __restrict__ X, float* state_emb) {
    int cx = blockIdx.x, b = blockIdx.y, d = threadIdx.x;
    int n0 = cx * 157, n1 = n0 + 157;
    if (n1 > N_NODES) n1 = N_NODES;
    float acc = 0.f;
    for (int n = n0; n < n1; n++) acc += X[(size_t)(n * 4 + b) * 128 + d];
    atomicAdd(&state_emb[b * 128 + d], acc);
}

__global__ __launch_bounds__(512) void beta_state_kernel(
    const float* __restrict__ state_emb, const float* __restrict__ W1,
    const float* __restrict__ b1, const float* __restrict__ W3, float* c1)
{
    __shared__ float sm[512];
    int tid = threadIdx.x;
    int b = tid >> 7, d = tid & 127;
    float acc = b1[d];
    for (int k = 0; k < 128; k++) acc += state_emb[b * 128 + k] * W1[k * 128 + d];
    float v = acc > 0.f ? acc : 0.f;
    sm[tid] = v * W3[d];
    __syncthreads();
    for (int s = 64; s > 0; s >>= 1) {
        if (d < s) sm[tid] += sm[tid + s];
        __syncthreads();
    }
    if (d == 0) c1[b] = sm[tid];
}

// ---------------- final: out = relu(X@W2 + b2).W3[128:] + c1[b] + b3 ----------------

__global__ __launch_bounds__(256) void final_mfma(
    const float* __restrict__ X,
    const unsigned short* __restrict__ WThi, const unsigned short* __restrict__ WTlo,
    const float* __restrict__ b2, const float* __restrict__ W3,
    const float* __restrict__ b3, const float* __restrict__ c1,
    float* __restrict__ out)
{
    __shared__ __align__(16) char smem[64 * PADK * 2 * 2];
    unsigned short* sAh = (unsigned short*)smem;
    unsigned short* sAl = sAh + 64 * PADK;
    __shared__ float sB2[128], sW3[128];
    __shared__ float sPart[64 * 4];

    int tid = threadIdx.x;
    int g0 = blockIdx.x * 64;
    int w = tid >> 6, lane = tid & 63;
    int quad = lane >> 4, mcol = lane & 15;

    if (tid < 128) { sB2[tid] = b2[tid]; sW3[tid] = W3[128 + tid]; }

    short8 Bh[4][2], Bl[4][2];
#pragma unroll
    for (int kc = 0; kc < 4; kc++)
#pragma unroll
        for (int nt = 0; nt < 2; nt++) {
            int col = w * 32 + nt * 16 + mcol;
            Bh[kc][nt] = *(const short8*)(WThi + col * 128 + kc * 32 + quad * 8);
            Bl[kc][nt] = *(const short8*)(WTlo + col * 128 + kc * 32 + quad * 8);
        }

    for (int i4 = tid; i4 < 64 * 32; i4 += 256) {
        int r = i4 >> 5, k4 = (i4 & 31) << 2;
        int g = g0 + r;
        float4 v = *(const float4*)(X + (size_t)g * 128 + k4);
        unsigned short h0 = f2bf(v.x), h1 = f2bf(v.y), h2 = f2bf(v.z), h3 = f2bf(v.w);
        short4v hv = { (short)h0, (short)h1, (short)h2, (short)h3 };
        short4v lv = { (short)f2bf(v.x - bf2f(h0)), (short)f2bf(v.y - bf2f(h1)),
                       (short)f2bf(v.z - bf2f(h2)), (short)f2bf(v.w - bf2f(h3)) };
        *(short4v*)(sAh + r * PADK + k4) = hv;
        *(short4v*)(sAl + r * PADK + k4) = lv;
    }
    __syncthreads();

    float4v acc[4][2];
#pragma unroll
    for (int mt = 0; mt < 4; mt++)
#pragma unroll
        for (int nt = 0; nt < 2; nt++) acc[mt][nt] = (float4v){0.f, 0.f, 0.f, 0.f};

#pragma unroll
    for (int kc = 0; kc < 4; kc++) {
#pragma unroll
        for (int mt = 0; mt < 4; mt++) {
            short8 ah = *(const short8*)(sAh + (mt * 16 + mcol) * PADK + kc * 32 + quad * 8);
            short8 al = *(const short8*)(sAl + (mt * 16 + mcol) * PADK + kc * 32 + quad * 8);
#pragma unroll
            for (int nt = 0; nt < 2; nt++) {
                acc[mt][nt] = __builtin_amdgcn_mfma_f32_16x16x32_bf16(ah, Bh[kc][nt], acc[mt][nt], 0, 0, 0);
                acc[mt][nt] = __builtin_amdgcn_mfma_f32_16x16x32_bf16(al, Bh[kc][nt], acc[mt][nt], 0, 0, 0);
                acc[mt][nt] = __builtin_amdgcn_mfma_f32_16x16x32_bf16(ah, Bl[kc][nt], acc[mt][nt], 0, 0, 0);
            }
        }
    }

    // epilogue: relu + W3 dot entirely in registers
    float pp[16];
#pragma unroll
    for (int r16 = 0; r16 < 16; r16++) pp[r16] = 0.f;
#pragma unroll
    for (int mt = 0; mt < 4; mt++)
#pragma unroll
        for (int nt = 0; nt < 2; nt++)
#pragma unroll
            for (int reg = 0; reg < 4; reg++) {
                int col = w * 32 + nt * 16 + mcol;
                float v = acc[mt][nt][reg] + sB2[col];
                v = v > 0.f ? v : 0.f;
                pp[mt * 4 + reg] += v * sW3[col];
            }
#pragma unroll
    for (int off = 1; off < 16; off <<= 1)
#pragma unroll
        for (int r16 = 0; r16 < 16; r16++)
            pp[r16] += __shfl_xor(pp[r16], off);
    if (mcol == 0) {
#pragma unroll
        for (int r16 = 0; r16 < 16; r16++) {
            int row = (r16 >> 2) * 16 + quad * 4 + (r16 & 3);
            sPart[row * 4 + w] = pp[r16];
        }
    }
    __syncthreads();
    if (tid < 64) {
        float p = sPart[tid * 4] + sPart[tid * 4 + 1] + sPart[tid * 4 + 2] + sPart[tid * 4 + 3];
        int g = g0 + tid;
        out[(g & 3) * N_NODES + (g >> 2)] = p + c1[g & 3] + b3[0];
    }
}

// ---------------- launch ----------------

extern "C" void kernel_launch(void* const* d_in, const int* in_sizes, int n_in,
                              void* d_out, int out_size, void* d_ws, size_t ws_size,
                              hipStream_t stream) {
    const float* state    = (const float*)d_in[0];   // [B,N]
    const float* strucEmb = (const float*)d_in[1];   // [N,128]
    const int*   edge_idx = (const int*)d_in[2];     // [2,Etot]
    const float* gat_W    = (const float*)d_in[3];   // [3,128,128]
    const float* gat_aS   = (const float*)d_in[4];
    const float* gat_aD   = (const float*)d_in[5];
    const float* gat_Wns  = (const float*)d_in[6];
    const float* gat_bns  = (const float*)d_in[7];
    const float* gat_bias = (const float*)d_in[8];
    const float* W1 = (const float*)d_in[9];
    const float* b1 = (const float*)d_in[10];
    const float* W2 = (const float*)d_in[11];
    const float* b2 = (const float*)d_in[12];
    const float* W3 = (const float*)d_in[13];
    const float* b3 = (const float*)d_in[14];
    float* out = (float*)d_out;

    int Etot = in_sizes[2] / 2;
    const int* srcArr = edge_idx;
    const int* dstArr = edge_idx + Etot;

    float* ws = (float*)d_ws;
    float* X           = ws;                   // 5,120,000 f (node-major [n*4+b][128] fp32)
    unsigned short* Hb = (unsigned short*)(ws + 5120000);  // 5,120,000 ushorts (node-major bf16) = 2.56M f
    float* aSrcP       = ws + 10240000;        // 40,000 f  ([n*4+b])
    float* aDstP       = ws + 10280000;        // 40,000 f
    float* state_emb   = ws + 10320000;        // 512 f
    float* c1          = ws + 10320512;        // 4 f
    unsigned short* whi = (unsigned short*)(ws + 10320516);  // 4*16384 ushorts = 32768 f
    unsigned short* wlo = whi + 4 * 16384;                   // 4*16384 ushorts = 32768 f
    int*   iws         = (int*)(ws + 10320516 + 65536);
    int*   rowOff      = iws;                  // N+1
    int*   deg         = iws + 10001;
    int*   cursor      = deg + 10000;
    int*   edgeLst     = cursor + 10000;       // Etot

    // weight preprocessing + CSR build (every call; graph-capture safe)
    wconv_kernel<<<dim3(64, 4), 256, 0, stream>>>(gat_W, W2, whi, wlo);
    init_kernel<<<40, 256, 0, stream>>>(deg, cursor, state_emb);
    hist_kernel<<<(Etot + 255) / 256, 256, 0, stream>>>(dstArr, Etot, deg);
    scan_kernel<<<1, 1024, 0, stream>>>(deg, rowOff);
    scatter_kernel<<<(Etot + 255) / 256, 256, 0, stream>>>(dstArr, Etot, rowOff, cursor, edgeLst);

    for (int l = 0; l < 3; l++) {
        gemm_att_mfma<<<BN / 64, 256, 0, stream>>>(
            l == 0 ? strucEmb : X, l == 0 ? 1 : 0, state,
            whi + (size_t)l * 16384, wlo + (size_t)l * 16384,
            gat_aS + l * 128, gat_aD + l * 128,
            gat_Wns + l * 128, gat_bns + l * 128, Hb, aSrcP, aDstP);
        sm_agg_kernel<<<N_NODES, 256, 0, stream>>>(
            rowOff, edgeLst, srcArr, aSrcP, aDstP, Hb, gat_bias + l * 128, X);
    }

    sum_nodes_kernel<<<dim3(64, B_SZ), 128, 0, stream>>>(X, state_emb);
    beta_state_kernel<<<1, 512, 0, stream>>>(state_emb, W1, b1, W3, c1);
    final_mfma<<<BN / 64, 256, 0, stream>>>(X, whi + 3 * 16384, wlo + 3 * 16384,
                                            b2, W3, b3, c1, out);
}

// Round 6
// 339.827 us; speedup vs baseline: 2.2152x; 1.0306x over previous
//
#include <hip/hip_runtime.h>
#include <math.h>

#define N_NODES 10000
#define B_SZ 4
#define SLOPE 0.01f
#define BN (B_SZ * N_NODES)
#define PADK 136   // ushorts per LDS C-row (272B, 16B-aligned)

typedef __attribute__((ext_vector_type(8))) short short8;
typedef __attribute__((ext_vector_type(4))) float float4v;

__device__ __forceinline__ unsigned short f2bf(float f) {
    unsigned u = __builtin_bit_cast(unsigned, f);
    u += 0x7fffu + ((u >> 16) & 1u);   // RNE
    return (unsigned short)(u >> 16);
}
__device__ __forceinline__ float bf2f(unsigned short s) {
    unsigned u = ((unsigned)s) << 16;
    return __builtin_bit_cast(float, u);
}

// ---------------- CSR build ----------------

__global__ __launch_bounds__(256) void init_kernel(int* deg, int* cursor, float* state_emb) {
    int i = blockIdx.x * 256 + threadIdx.x;
    if (i < N_NODES) { deg[i] = 0; cursor[i] = 0; }
    if (i < B_SZ * 128) state_emb[i] = 0.f;
}

__global__ __launch_bounds__(256) void hist_kernel(const int* __restrict__ dst, int Etot, int* deg) {
    int e = blockIdx.x * 256 + threadIdx.x;
    if (e < Etot) atomicAdd(&deg[dst[e]], 1);
}

__global__ __launch_bounds__(1024) void scan_kernel(const int* __restrict__ deg, int* __restrict__ rowOff) {
    __shared__ int wsum[16];
    int tid = threadIdx.x;
    int lane = tid & 63, wid = tid >> 6;
    int base = tid * 10;
    int v[10]; int tot = 0;
#pragma unroll
    for (int j = 0; j < 10; j++) {
        int idx = base + j;
        int d = (idx < N_NODES) ? deg[idx] : 0;
        tot += d; v[j] = tot;
    }
    int incl = tot;
    for (int off = 1; off < 64; off <<= 1) {
        int t = __shfl_up(incl, off, 64);
        if (lane >= off) incl += t;
    }
    if (lane == 63) wsum[wid] = incl;
    __syncthreads();
    if (wid == 0) {
        int wv = (lane < 16) ? wsum[lane] : 0;
        for (int off = 1; off < 16; off <<= 1) {
            int t = __shfl_up(wv, off, 64);
            if (lane >= off) wv += t;
        }
        if (lane < 16) wsum[lane] = wv;
    }
    __syncthreads();
    int waveoff = (wid > 0) ? wsum[wid - 1] : 0;
    int excl = waveoff + incl - tot;
    if (tid == 0) rowOff[0] = 0;
#pragma unroll
    for (int j = 0; j < 10; j++) {
        int idx = base + j;
        if (idx < N_NODES) rowOff[idx + 1] = excl + v[j];
    }
}

__global__ __launch_bounds__(256) void scatter_kernel(const int* __restrict__ dst, int Etot,
                                                      const int* __restrict__ rowOff,
                                                      int* cursor, int* __restrict__ edgeLst) {
    int e = blockIdx.x * 256 + threadIdx.x;
    if (e < Etot) {
        int d = dst[e];
        int pos = rowOff[d] + atomicAdd(&cursor[d], 1);
        edgeLst[pos] = e;
    }
}

// ---------------- weight preprocessing: W[k][c] -> WT hi/lo bf16 [c][k] ----------------

__global__ __launch_bounds__(256) void wconv_kernel(const float* __restrict__ gatW,
                                                    const float* __restrict__ W2,
                                                    unsigned short* __restrict__ whi,
                                                    unsigned short* __restrict__ wlo) {
    int w = blockIdx.y;
    int i = blockIdx.x * 256 + threadIdx.x;
    int k = i >> 7, c = i & 127;
    const float* src = (w < 3) ? (gatW + (size_t)w * 16384) : W2;
    float v = src[k * 128 + c];
    unsigned short h = f2bf(v);
    whi[w * 16384 + c * 128 + k] = h;
    wlo[w * 16384 + c * 128 + k] = f2bf(v - bf2f(h));
}

// ---------------- layer-0 input prep: XS0 = bf16(strucEmb + state*Wns0 + bns0), node-major ----------------

__global__ __launch_bounds__(256) void prep0_kernel(const float* __restrict__ strucEmb,
                                                    const float* __restrict__ state,
                                                    const float* __restrict__ Wns0,
                                                    const float* __restrict__ bns0,
                                                    unsigned short* __restrict__ XS) {
    int idx = blockIdx.x * 256 + threadIdx.x;   // 0 .. BN*128-1
    int g = idx >> 7, d = idx & 127;
    int n = g >> 2, b = g & 3;
    float v = strucEmb[(size_t)n * 128 + d] + state[b * N_NODES + n] * Wns0[d] + bns0[d];
    XS[idx] = f2bf(v);
}

// ---------------- MFMA GEMM (GAT layer): H(bf16) = XS(bf16) @ W ; att dots ----------------
// A fragments loaded straight from global (XS already bf16). 2-term MFMA (Bh,Bl).

__global__ __launch_bounds__(256) void gemm_att_mfma(
    const unsigned short* __restrict__ XS,   // [g][128] bf16 node-major
    const unsigned short* __restrict__ WThi, const unsigned short* __restrict__ WTlo,
    const float* __restrict__ attS, const float* __restrict__ attD,
    unsigned short* __restrict__ Hout, float* __restrict__ aSrcP, float* __restrict__ aDstP)
{
    __shared__ __align__(16) unsigned short sCus[64 * PADK];  // 17408 B
    __shared__ float sAs[128], sAd[128];
    __shared__ float sPart[64 * 8];

    int tid = threadIdx.x;
    int g0 = blockIdx.x * 64;
    int w = tid >> 6, lane = tid & 63;
    int quad = lane >> 4, mcol = lane & 15;

    if (tid < 128) { sAs[tid] = attS[tid]; sAd[tid] = attD[tid]; }

    short8 Bh[4][2], Bl[4][2];
#pragma unroll
    for (int kc = 0; kc < 4; kc++)
#pragma unroll
        for (int nt = 0; nt < 2; nt++) {
            int col = w * 32 + nt * 16 + mcol;
            Bh[kc][nt] = *(const short8*)(WThi + col * 128 + kc * 32 + quad * 8);
            Bl[kc][nt] = *(const short8*)(WTlo + col * 128 + kc * 32 + quad * 8);
        }
    short8 Af[4][4];  // [mt][kc]
#pragma unroll
    for (int mt = 0; mt < 4; mt++)
#pragma unroll
        for (int kc = 0; kc < 4; kc++)
            Af[mt][kc] = *(const short8*)(XS + (size_t)(g0 + mt * 16 + mcol) * 128 + kc * 32 + quad * 8);

    float4v acc[4][2];
#pragma unroll
    for (int mt = 0; mt < 4; mt++)
#pragma unroll
        for (int nt = 0; nt < 2; nt++) acc[mt][nt] = (float4v){0.f, 0.f, 0.f, 0.f};

#pragma unroll
    for (int kc = 0; kc < 4; kc++)
#pragma unroll
        for (int mt = 0; mt < 4; mt++)
#pragma unroll
            for (int nt = 0; nt < 2; nt++) {
                acc[mt][nt] = __builtin_amdgcn_mfma_f32_16x16x32_bf16(Af[mt][kc], Bh[kc][nt], acc[mt][nt], 0, 0, 0);
                acc[mt][nt] = __builtin_amdgcn_mfma_f32_16x16x32_bf16(Af[mt][kc], Bl[kc][nt], acc[mt][nt], 0, 0, 0);
            }

    __syncthreads();   // sAs/sAd visible; nothing else touched sCus yet

    float pp[16], pd[16];
#pragma unroll
    for (int r16 = 0; r16 < 16; r16++) { pp[r16] = 0.f; pd[r16] = 0.f; }
#pragma unroll
    for (int mt = 0; mt < 4; mt++)
#pragma unroll
        for (int nt = 0; nt < 2; nt++)
#pragma unroll
            for (int reg = 0; reg < 4; reg++) {
                int row = mt * 16 + quad * 4 + reg;   // C/D: col=lane&15, row=quad*4+reg
                int col = w * 32 + nt * 16 + mcol;
                float v = acc[mt][nt][reg];
                sCus[row * PADK + col] = f2bf(v);
                pp[mt * 4 + reg] += v * sAs[col];
                pd[mt * 4 + reg] += v * sAd[col];
            }
#pragma unroll
    for (int off = 1; off < 16; off <<= 1)
#pragma unroll
        for (int r16 = 0; r16 < 16; r16++) {
            pp[r16] += __shfl_xor(pp[r16], off);
            pd[r16] += __shfl_xor(pd[r16], off);
        }
    if (mcol == 0) {
#pragma unroll
        for (int r16 = 0; r16 < 16; r16++) {
            int row = (r16 >> 2) * 16 + quad * 4 + (r16 & 3);
            sPart[row * 8 + w * 2 + 0] = pp[r16];
            sPart[row * 8 + w * 2 + 1] = pd[r16];
        }
    }
    __syncthreads();

    // coalesced bf16 H write: uint4 = 8 ushorts, c8 in 0..15
    for (int i = tid; i < 64 * 16; i += 256) {
        int r = i >> 4, c8 = i & 15;
        uint4 u = *(uint4*)(sCus + r * PADK + c8 * 8);
        *(uint4*)(Hout + (size_t)(g0 + r) * 128 + c8 * 8) = u;
    }
    if (tid < 64) {
        float s0 = sPart[tid * 8] + sPart[tid * 8 + 2] + sPart[tid * 8 + 4] + sPart[tid * 8 + 6];
        float s1 = sPart[tid * 8 + 1] + sPart[tid * 8 + 3] + sPart[tid * 8 + 5] + sPart[tid * 8 + 7];
        aSrcP[g0 + tid] = s0;
        aDstP[g0 + tid] = s1;
    }
}

// ---------------- fused softmax + aggregate (+ next-layer Wns/bns add), bf16 in/out ----------------
// one block per node; wave b = batch b. Fast path (deg<=64): single gather + fused exp/sum/accumulate.

__global__ __launch_bounds__(256) void sm_agg_kernel(
    const int* __restrict__ rowOff, const int* __restrict__ edgeLst,
    const int* __restrict__ srcArr,
    const float* __restrict__ aSrcP, const float* __restrict__ aDstP,
    const unsigned short* __restrict__ H,    // [n*4+b][128] bf16
    const float* __restrict__ bias,
    const float* __restrict__ state, const float* __restrict__ wnsN,
    const float* __restrict__ bnsN, int addNext,
    unsigned short* __restrict__ Xout)       // [n*4+b][128] bf16
{
    __shared__ int sSrc[64];
    __shared__ float sAe[64 * 4];
    int n = blockIdx.x;
    int start = rowOff[n], end = rowOff[n + 1];
    int cnt = end - start;
    int tid = threadIdx.x;
    int b = tid >> 6, t = tid & 63;
    float adst = aDstP[n * 4 + b];
    const unsigned int* Hu = (const unsigned int*)H;

    float accx = 0.f, accy = 0.f, inv = 0.f;

    if (cnt <= 64) {
        float ae = -1e30f;
        if (t < cnt) {
            int e = edgeLst[start + t];
            int sn = srcArr[e];
            if (b == 0) sSrc[t] = sn;
            float v = aSrcP[sn * 4 + b] + adst;
            ae = v > 0.f ? v : SLOPE * v;
            sAe[t * 4 + b] = ae;
        }
        float m = ae;
        m = fmaxf(m, __shfl_xor(m, 1));  m = fmaxf(m, __shfl_xor(m, 2));
        m = fmaxf(m, __shfl_xor(m, 4));  m = fmaxf(m, __shfl_xor(m, 8));
        m = fmaxf(m, __shfl_xor(m, 16)); m = fmaxf(m, __shfl_xor(m, 32));
        __syncthreads();
        float s = 0.f;
        int j = 0;
        for (; j + 4 <= cnt; j += 4) {
            float a0 = __expf(sAe[j * 4 + b] - m),       a1 = __expf(sAe[(j + 1) * 4 + b] - m);
            float a2 = __expf(sAe[(j + 2) * 4 + b] - m), a3 = __expf(sAe[(j + 3) * 4 + b] - m);
            int s0 = sSrc[j], s1 = sSrc[j + 1], s2 = sSrc[j + 2], s3 = sSrc[j + 3];
            s += a0 + a1 + a2 + a3;
            unsigned int h0 = Hu[(size_t)(s0 * 4 + b) * 64 + t];
            unsigned int h1 = Hu[(size_t)(s1 * 4 + b) * 64 + t];
            unsigned int h2 = Hu[(size_t)(s2 * 4 + b) * 64 + t];
            unsigned int h3 = Hu[(size_t)(s3 * 4 + b) * 64 + t];
            accx += a0 * __builtin_bit_cast(float, h0 << 16) + a1 * __builtin_bit_cast(float, h1 << 16)
                  + a2 * __builtin_bit_cast(float, h2 << 16) + a3 * __builtin_bit_cast(float, h3 << 16);
            accy += a0 * __builtin_bit_cast(float, h0 & 0xffff0000u) + a1 * __builtin_bit_cast(float, h1 & 0xffff0000u)
                  + a2 * __builtin_bit_cast(float, h2 & 0xffff0000u) + a3 * __builtin_bit_cast(float, h3 & 0xffff0000u);
        }
        for (; j < cnt; j++) {
            float a0 = __expf(sAe[j * 4 + b] - m);
            int s0 = sSrc[j];
            s += a0;
            unsigned int h0 = Hu[(size_t)(s0 * 4 + b) * 64 + t];
            accx += a0 * __builtin_bit_cast(float, h0 << 16);
            accy += a0 * __builtin_bit_cast(float, h0 & 0xffff0000u);
        }
        inv = 1.f / s;
    } else {
        // 3-pass fallback (block-uniform branch; barriers safe)
        float m = -1e30f;
        for (int i = start + t; i < end; i += 64) {
            int sn = srcArr[edgeLst[i]];
            float v = aSrcP[sn * 4 + b] + adst;
            m = fmaxf(m, v > 0.f ? v : SLOPE * v);
        }
        m = fmaxf(m, __shfl_xor(m, 1));  m = fmaxf(m, __shfl_xor(m, 2));
        m = fmaxf(m, __shfl_xor(m, 4));  m = fmaxf(m, __shfl_xor(m, 8));
        m = fmaxf(m, __shfl_xor(m, 16)); m = fmaxf(m, __shfl_xor(m, 32));
        float s = 0.f;
        for (int i = start + t; i < end; i += 64) {
            int sn = srcArr[edgeLst[i]];
            float v = aSrcP[sn * 4 + b] + adst;
            float ae = v > 0.f ? v : SLOPE * v;
            s += __expf(ae - m);
        }
        s += __shfl_xor(s, 1);  s += __shfl_xor(s, 2);  s += __shfl_xor(s, 4);
        s += __shfl_xor(s, 8);  s += __shfl_xor(s, 16); s += __shfl_xor(s, 32);
        for (int c0 = start; c0 < end; c0 += 64) {
            int c = min(64, end - c0);
            if (t < c) {
                int e = edgeLst[c0 + t];
                int sn = srcArr[e];
                if (b == 0) sSrc[t] = sn;
                float v = aSrcP[sn * 4 + b] + adst;
                float ae = v > 0.f ? v : SLOPE * v;
                sAe[t * 4 + b] = __expf(ae - m);
            }
            __syncthreads();
            for (int j = 0; j < c; j++) {
                float a0 = sAe[j * 4 + b];
                int s0 = sSrc[j];
                unsigned int h0 = Hu[(size_t)(s0 * 4 + b) * 64 + t];
                accx += a0 * __builtin_bit_cast(float, h0 << 16);
                accy += a0 * __builtin_bit_cast(float, h0 & 0xffff0000u);
            }
            __syncthreads();
        }
        inv = 1.f / s;
    }

    float ox = accx * inv + bias[2 * t];
    float oy = accy * inv + bias[2 * t + 1];
    ox = ox > 0.f ? ox : 0.f;
    oy = oy > 0.f ? oy : 0.f;
    if (addNext) {
        float st = state[b * N_NODES + n];
        ox += st * wnsN[2 * t]     + bnsN[2 * t];
        oy += st * wnsN[2 * t + 1] + bnsN[2 * t + 1];
    }
    unsigned px = f2bf(ox), py = f2bf(oy);
    ((unsigned*)Xout)[(size_t)(n * 4 + b) * 64 + t] = (py << 16) | px;
}

// ---------------- head ----------------

__global__ __launch_bounds__(128) void sum_nodes_kernel(const unsigned short* __restrict__ X, float* state_emb) {
    int cx = blockIdx.x, b = blockIdx.y, d = threadIdx.x;
    int n0 = cx * 157, n1 = n0 + 157;
    if (n1 > N_NODES) n1 = N_NODES;
    float acc = 0.f;
    for (int n = n0; n < n1; n++) acc += bf2f(X[(size_t)(n * 4 + b) * 128 + d]);
    atomicAdd(&state_emb[b * 128 + d], acc);
}

__global__ __launch_bounds__(512) void beta_state_kernel(
    const float* __restrict__ state_emb, const float* __restrict__ W1,
    const float* __restrict__ b1, const float* __restrict__ W3, float* c1)
{
    __shared__ float sm[512];
    int tid = threadIdx.x;
    int b = tid >> 7, d = tid & 127;
    float acc = b1[d];
    for (int k = 0; k < 128; k++) acc += state_emb[b * 128 + k] * W1[k * 128 + d];
    float v = acc > 0.f ? acc : 0.f;
    sm[tid] = v * W3[d];
    __syncthreads();
    for (int s = 64; s > 0; s >>= 1) {
        if (d < s) sm[tid] += sm[tid + s];
        __syncthreads();
    }
    if (d == 0) c1[b] = sm[tid];
}

// ---------------- final: out = relu(X3@W2 + b2).W3[128:] + c1[b] + b3 ----------------

__global__ __launch_bounds__(256) void final_mfma(
    const unsigned short* __restrict__ X,    // bf16 node-major
    const unsigned short* __restrict__ WThi, const unsigned short* __restrict__ WTlo,
    const float* __restrict__ b2, const float* __restrict__ W3,
    const float* __restrict__ b3, const float* __restrict__ c1,
    float* __restrict__ out)
{
    __shared__ float sB2[128], sW3[128];
    __shared__ float sPart[64 * 4];

    int tid = threadIdx.x;
    int g0 = blockIdx.x * 64;
    int w = tid >> 6, lane = tid & 63;
    int quad = lane >> 4, mcol = lane & 15;

    if (tid < 128) { sB2[tid] = b2[tid]; sW3[tid] = W3[128 + tid]; }

    short8 Bh[4][2], Bl[4][2];
#pragma unroll
    for (int kc = 0; kc < 4; kc++)
#pragma unroll
        for (int nt = 0; nt < 2; nt++) {
            int col = w * 32 + nt * 16 + mcol;
            Bh[kc][nt] = *(const short8*)(WThi + col * 128 + kc * 32 + quad * 8);
            Bl[kc][nt] = *(const short8*)(WTlo + col * 128 + kc * 32 + quad * 8);
        }
    short8 Af[4][4];
#pragma unroll
    for (int mt = 0; mt < 4; mt++)
#pragma unroll
        for (int kc = 0; kc < 4; kc++)
            Af[mt][kc] = *(const short8*)(X + (size_t)(g0 + mt * 16 + mcol) * 128 + kc * 32 + quad * 8);

    float4v acc[4][2];
#pragma unroll
    for (int mt = 0; mt < 4; mt++)
#pragma unroll
        for (int nt = 0; nt < 2; nt++) acc[mt][nt] = (float4v){0.f, 0.f, 0.f, 0.f};

#pragma unroll
    for (int kc = 0; kc < 4; kc++)
#pragma unroll
        for (int mt = 0; mt < 4; mt++)
#pragma unroll
            for (int nt = 0; nt < 2; nt++) {
                acc[mt][nt] = __builtin_amdgcn_mfma_f32_16x16x32_bf16(Af[mt][kc], Bh[kc][nt], acc[mt][nt], 0, 0, 0);
                acc[mt][nt] = __builtin_amdgcn_mfma_f32_16x16x32_bf16(Af[mt][kc], Bl[kc][nt], acc[mt][nt], 0, 0, 0);
            }

    __syncthreads();   // sB2/sW3 visible

    float pp[16];
#pragma unroll
    for (int r16 = 0; r16 < 16; r16++) pp[r16] = 0.f;
#pragma unroll
    for (int mt = 0; mt < 4; mt++)
#pragma unroll
        for (int nt = 0; nt < 2; nt++)
#pragma unroll
            for (int reg = 0; reg < 4; reg++) {
                int col = w * 32 + nt * 16 + mcol;
                float v = acc[mt][nt][reg] + sB2[col];
                v = v > 0.f ? v : 0.f;
                pp[mt * 4 + reg] += v * sW3[col];
            }
#pragma unroll
    for (int off = 1; off < 16; off <<= 1)
#pragma unroll
        for (int r16 = 0; r16 < 16; r16++)
            pp[r16] += __shfl_xor(pp[r16], off);
    if (mcol == 0) {
#pragma unroll
        for (int r16 = 0; r16 < 16; r16++) {
            int row = (r16 >> 2) * 16 + quad * 4 + (r16 & 3);
            sPart[row * 4 + w] = pp[r16];
        }
    }
    __syncthreads();
    if (tid < 64) {
        float p = sPart[tid * 4] + sPart[tid * 4 + 1] + sPart[tid * 4 + 2] + sPart[tid * 4 + 3];
        int g = g0 + tid;
        out[(g & 3) * N_NODES + (g >> 2)] = p + c1[g & 3] + b3[0];
    }
}

// ---------------- launch ----------------

extern "C" void kernel_launch(void* const* d_in, const int* in_sizes, int n_in,
                              void* d_out, int out_size, void* d_ws, size_t ws_size,
                              hipStream_t stream) {
    const float* state    = (const float*)d_in[0];   // [B,N]
    const float* strucEmb = (const float*)d_in[1];   // [N,128]
    const int*   edge_idx = (const int*)d_in[2];     // [2,Etot]
    const float* gat_W    = (const float*)d_in[3];   // [3,128,128]
    const float* gat_aS   = (const float*)d_in[4];
    const float* gat_aD   = (const float*)d_in[5];
    const float* gat_Wns  = (const float*)d_in[6];
    const float* gat_bns  = (const float*)d_in[7];
    const float* gat_bias = (const float*)d_in[8];
    const float* W1 = (const float*)d_in[9];
    const float* b1 = (const float*)d_in[10];
    const float* W2 = (const float*)d_in[11];
    const float* b2 = (const float*)d_in[12];
    const float* W3 = (const float*)d_in[13];
    const float* b3 = (const float*)d_in[14];
    float* out = (float*)d_out;

    int Etot = in_sizes[2] / 2;
    const int* srcArr = edge_idx;
    const int* dstArr = edge_idx + Etot;

    float* ws = (float*)d_ws;
    unsigned short* Xb = (unsigned short*)ws;              // 5,120,000 us = 2,560,000 f
    unsigned short* Hb = (unsigned short*)(ws + 2560000);  // 5,120,000 us
    float* aSrcP       = ws + 5120000;                     // 40,000 f
    float* aDstP       = ws + 5160000;                     // 40,000 f
    float* state_emb   = ws + 5200000;                     // 512 f
    float* c1          = ws + 5200512;                     // 4 f
    unsigned short* whi = (unsigned short*)(ws + 5200516); // 65,536 us = 32,768 f
    unsigned short* wlo = whi + 4 * 16384;                 // 65,536 us = 32,768 f
    int*   iws         = (int*)(ws + 5200516 + 65536);
    int*   rowOff      = iws;                              // N+1
    int*   deg         = iws + 10001;
    int*   cursor      = deg + 10000;
    int*   edgeLst     = cursor + 10000;                   // Etot

    wconv_kernel<<<dim3(64, 4), 256, 0, stream>>>(gat_W, W2, whi, wlo);
    init_kernel<<<40, 256, 0, stream>>>(deg, cursor, state_emb);
    prep0_kernel<<<BN * 128 / 256, 256, 0, stream>>>(strucEmb, state, gat_Wns, gat_bns, Xb);
    hist_kernel<<<(Etot + 255) / 256, 256, 0, stream>>>(dstArr, Etot, deg);
    scan_kernel<<<1, 1024, 0, stream>>>(deg, rowOff);
    scatter_kernel<<<(Etot + 255) / 256, 256, 0, stream>>>(dstArr, Etot, rowOff, cursor, edgeLst);

    for (int l = 0; l < 3; l++) {
        gemm_att_mfma<<<BN / 64, 256, 0, stream>>>(
            Xb, whi + (size_t)l * 16384, wlo + (size_t)l * 16384,
            gat_aS + l * 128, gat_aD + l * 128, Hb, aSrcP, aDstP);
        sm_agg_kernel<<<N_NODES, 256, 0, stream>>>(
            rowOff, edgeLst, srcArr, aSrcP, aDstP, Hb, gat_bias + l * 128,
            state, gat_Wns + (l + 1 < 3 ? (l + 1) * 128 : 0),
            gat_bns + (l + 1 < 3 ? (l + 1) * 128 : 0), (l < 2) ? 1 : 0, Xb);
    }

    sum_nodes_kernel<<<dim3(64, B_SZ), 128, 0, stream>>>(Xb, state_emb);
    beta_state_kernel<<<1, 512, 0, stream>>>(state_emb, W1, b1, W3, c1);
    final_mfma<<<BN / 64, 256, 0, stream>>>(Xb, whi + 3 * 16384, wlo + 3 * 16384,
                                            b2, W3, b3, c1, out);
}

// Round 7
// 337.336 us; speedup vs baseline: 2.2316x; 1.0074x over previous
//
#include <hip/hip_runtime.h>
#include <math.h>

#define N_NODES 10000
#define B_SZ 4
#define SLOPE 0.01f
#define BN (B_SZ * N_NODES)
#define PADK 136   // ushorts per LDS C-row (272B, 16B-aligned)

typedef __attribute__((ext_vector_type(8))) short short8;
typedef __attribute__((ext_vector_type(4))) float float4v;

__device__ __forceinline__ unsigned short f2bf(float f) {
    unsigned u = __builtin_bit_cast(unsigned, f);
    u += 0x7fffu + ((u >> 16) & 1u);   // RNE
    return (unsigned short)(u >> 16);
}
__device__ __forceinline__ float bf2f(unsigned short s) {
    unsigned u = ((unsigned)s) << 16;
    return __builtin_bit_cast(float, u);
}
__device__ __forceinline__ float bflo(unsigned u) { return __builtin_bit_cast(float, u << 16); }
__device__ __forceinline__ float bfhi(unsigned u) { return __builtin_bit_cast(float, u & 0xffff0000u); }

// ---------------- fused setup: prep0 + wconv + init ----------------
// blocks [0,20000): XS0 = bf16(strucEmb + state*Wns0 + bns0)
// blocks [20000,20256): W -> WT hi/lo bf16 [c][k]
// blocks [20256,20296): zero deg/cursor/state_emb

__global__ __launch_bounds__(256) void setup_kernel(
    const float* __restrict__ strucEmb, const float* __restrict__ state,
    const float* __restrict__ Wns0, const float* __restrict__ bns0,
    const float* __restrict__ gatW, const float* __restrict__ W2,
    unsigned short* __restrict__ XS,
    unsigned short* __restrict__ whi, unsigned short* __restrict__ wlo,
    int* deg, int* cursor, float* state_emb)
{
    int bx = blockIdx.x, tid = threadIdx.x;
    if (bx < 20000) {
        int idx = bx * 256 + tid;
        int g = idx >> 7, d = idx & 127;
        int n = g >> 2, b = g & 3;
        float v = strucEmb[(size_t)n * 128 + d] + state[b * N_NODES + n] * Wns0[d] + bns0[d];
        XS[idx] = f2bf(v);
    } else if (bx < 20256) {
        int i = (bx - 20000) * 256 + tid;     // 0..65535
        int w = i >> 14, rem = i & 16383;
        int k = rem >> 7, c = rem & 127;
        const float* src = (w < 3) ? (gatW + (size_t)w * 16384) : W2;
        float v = src[k * 128 + c];
        unsigned short h = f2bf(v);
        whi[w * 16384 + c * 128 + k] = h;
        wlo[w * 16384 + c * 128 + k] = f2bf(v - bf2f(h));
    } else {
        int i = (bx - 20256) * 256 + tid;
        if (i < N_NODES) { deg[i] = 0; cursor[i] = 0; }
        if (i < 512) state_emb[i] = 0.f;
    }
}

// ---------------- CSR build ----------------

__global__ __launch_bounds__(256) void hist_kernel(const int* __restrict__ dst, int Etot, int* deg) {
    int e = blockIdx.x * 256 + threadIdx.x;
    if (e < Etot) atomicAdd(&deg[dst[e]], 1);
}

__global__ __launch_bounds__(1024) void scan_kernel(const int* __restrict__ deg, int* __restrict__ rowOff) {
    __shared__ int wsum[16];
    int tid = threadIdx.x;
    int lane = tid & 63, wid = tid >> 6;
    int base = tid * 10;
    int v[10]; int tot = 0;
#pragma unroll
    for (int j = 0; j < 10; j++) {
        int idx = base + j;
        int d = (idx < N_NODES) ? deg[idx] : 0;
        tot += d; v[j] = tot;
    }
    int incl = tot;
    for (int off = 1; off < 64; off <<= 1) {
        int t = __shfl_up(incl, off, 64);
        if (lane >= off) incl += t;
    }
    if (lane == 63) wsum[wid] = incl;
    __syncthreads();
    if (wid == 0) {
        int wv = (lane < 16) ? wsum[lane] : 0;
        for (int off = 1; off < 16; off <<= 1) {
            int t = __shfl_up(wv, off, 64);
            if (lane >= off) wv += t;
        }
        if (lane < 16) wsum[lane] = wv;
    }
    __syncthreads();
    int waveoff = (wid > 0) ? wsum[wid - 1] : 0;
    int excl = waveoff + incl - tot;
    if (tid == 0) rowOff[0] = 0;
#pragma unroll
    for (int j = 0; j < 10; j++) {
        int idx = base + j;
        if (idx < N_NODES) rowOff[idx + 1] = excl + v[j];
    }
}

// scatter writes source node id directly (kills one indirection in sm_agg)
__global__ __launch_bounds__(256) void scatter_kernel(const int* __restrict__ src, const int* __restrict__ dst,
                                                      int Etot, const int* __restrict__ rowOff,
                                                      int* cursor, int* __restrict__ srcLst) {
    int e = blockIdx.x * 256 + threadIdx.x;
    if (e < Etot) {
        int d = dst[e];
        int pos = rowOff[d] + atomicAdd(&cursor[d], 1);
        srcLst[pos] = src[e];
    }
}

// ---------------- MFMA GEMM (GAT layer): H(bf16) = XS(bf16) @ W ; att dots ----------------
// sequential hi/lo term loop keeps only one B-set live (VGPR diet -> higher occupancy)

__global__ __launch_bounds__(256) void gemm_att_mfma(
    const unsigned short* __restrict__ XS,
    const unsigned short* __restrict__ WThi, const unsigned short* __restrict__ WTlo,
    const float* __restrict__ attS, const float* __restrict__ attD,
    unsigned short* __restrict__ Hout, float* __restrict__ aSrcP, float* __restrict__ aDstP)
{
    __shared__ __align__(16) unsigned short sCus[64 * PADK];
    __shared__ float sAs[128], sAd[128];
    __shared__ float sPart[64 * 8];

    int tid = threadIdx.x;
    int g0 = blockIdx.x * 64;
    int w = tid >> 6, lane = tid & 63;
    int quad = lane >> 4, mcol = lane & 15;

    if (tid < 128) { sAs[tid] = attS[tid]; sAd[tid] = attD[tid]; }

    float4v acc[4][2];
#pragma unroll
    for (int mt = 0; mt < 4; mt++)
#pragma unroll
        for (int nt = 0; nt < 2; nt++) acc[mt][nt] = (float4v){0.f, 0.f, 0.f, 0.f};

#pragma unroll 1
    for (int term = 0; term < 2; term++) {
        const unsigned short* WT = term ? WTlo : WThi;
        short8 Bf[4][2];
#pragma unroll
        for (int kc = 0; kc < 4; kc++)
#pragma unroll
            for (int nt = 0; nt < 2; nt++)
                Bf[kc][nt] = *(const short8*)(WT + (w * 32 + nt * 16 + mcol) * 128 + kc * 32 + quad * 8);
#pragma unroll
        for (int kc = 0; kc < 4; kc++) {
            short8 Aa[4];
#pragma unroll
            for (int mt = 0; mt < 4; mt++)
                Aa[mt] = *(const short8*)(XS + (size_t)(g0 + mt * 16 + mcol) * 128 + kc * 32 + quad * 8);
#pragma unroll
            for (int mt = 0; mt < 4; mt++)
#pragma unroll
                for (int nt = 0; nt < 2; nt++)
                    acc[mt][nt] = __builtin_amdgcn_mfma_f32_16x16x32_bf16(Aa[mt], Bf[kc][nt], acc[mt][nt], 0, 0, 0);
        }
    }

    __syncthreads();   // sAs/sAd visible

    float pp[16], pd[16];
#pragma unroll
    for (int r16 = 0; r16 < 16; r16++) { pp[r16] = 0.f; pd[r16] = 0.f; }
#pragma unroll
    for (int mt = 0; mt < 4; mt++)
#pragma unroll
        for (int nt = 0; nt < 2; nt++)
#pragma unroll
            for (int reg = 0; reg < 4; reg++) {
                int row = mt * 16 + quad * 4 + reg;   // C/D: col=lane&15, row=quad*4+reg
                int col = w * 32 + nt * 16 + mcol;
                float v = acc[mt][nt][reg];
                sCus[row * PADK + col] = f2bf(v);
                pp[mt * 4 + reg] += v * sAs[col];
                pd[mt * 4 + reg] += v * sAd[col];
            }
#pragma unroll
    for (int off = 1; off < 16; off <<= 1)
#pragma unroll
        for (int r16 = 0; r16 < 16; r16++) {
            pp[r16] += __shfl_xor(pp[r16], off);
            pd[r16] += __shfl_xor(pd[r16], off);
        }
    if (mcol == 0) {
#pragma unroll
        for (int r16 = 0; r16 < 16; r16++) {
            int row = (r16 >> 2) * 16 + quad * 4 + (r16 & 3);
            sPart[row * 8 + w * 2 + 0] = pp[r16];
            sPart[row * 8 + w * 2 + 1] = pd[r16];
        }
    }
    __syncthreads();

    for (int i = tid; i < 64 * 16; i += 256) {
        int r = i >> 4, c8 = i & 15;
        uint4 u = *(uint4*)(sCus + r * PADK + c8 * 8);
        *(uint4*)(Hout + (size_t)(g0 + r) * 128 + c8 * 8) = u;
    }
    if (tid < 64) {
        float s0 = sPart[tid * 8] + sPart[tid * 8 + 2] + sPart[tid * 8 + 4] + sPart[tid * 8 + 6];
        float s1 = sPart[tid * 8 + 1] + sPart[tid * 8 + 3] + sPart[tid * 8 + 5] + sPart[tid * 8 + 7];
        aSrcP[g0 + tid] = s0;
        aDstP[g0 + tid] = s1;
    }
}

// ---------------- fused softmax + aggregate (+ next-layer Wns/bns), bf16 in/out ----------------
// fast path: alpha precomputed into LDS; gather = 2 edges/wave, 8B (uint2) per lane.

__global__ __launch_bounds__(256) void sm_agg_kernel(
    const int* __restrict__ rowOff, const int* __restrict__ srcLst,
    const float* __restrict__ aSrcP, const float* __restrict__ aDstP,
    const unsigned short* __restrict__ H,
    const float* __restrict__ bias,
    const float* __restrict__ state, const float* __restrict__ wnsN,
    const float* __restrict__ bnsN, int addNext,
    unsigned short* __restrict__ Xout)
{
    __shared__ int sSrc[64];
    __shared__ float sAe[64 * 4];
    int n = blockIdx.x;
    int start = rowOff[n], end = rowOff[n + 1];
    int cnt = end - start;
    int tid = threadIdx.x;
    int b = tid >> 6, t = tid & 63;
    float adst = aDstP[n * 4 + b];
    const unsigned* Hu = (const unsigned*)H;

    if (cnt <= 64) {
        float ae = -1e30f;
        if (t < cnt) {
            int sn = srcLst[start + t];
            if (b == 0) sSrc[t] = sn;
            float v = aSrcP[sn * 4 + b] + adst;
            ae = v > 0.f ? v : SLOPE * v;
        }
        float m = ae;
        m = fmaxf(m, __shfl_xor(m, 1));  m = fmaxf(m, __shfl_xor(m, 2));
        m = fmaxf(m, __shfl_xor(m, 4));  m = fmaxf(m, __shfl_xor(m, 8));
        m = fmaxf(m, __shfl_xor(m, 16)); m = fmaxf(m, __shfl_xor(m, 32));
        float e = (t < cnt) ? __expf(ae - m) : 0.f;
        float s = e;
        s += __shfl_xor(s, 1);  s += __shfl_xor(s, 2);  s += __shfl_xor(s, 4);
        s += __shfl_xor(s, 8);  s += __shfl_xor(s, 16); s += __shfl_xor(s, 32);
        float inv = 1.f / s;
        if (t < cnt) sAe[t * 4 + b] = e * inv;   // alpha
        __syncthreads();

        int half = t >> 5, cc = t & 31;
        float a0 = 0.f, a1 = 0.f, a2 = 0.f, a3 = 0.f;
        int j = 0;
        for (; j + 8 <= cnt; j += 8) {
            int j0 = j + half, j1 = j + 2 + half, j2 = j + 4 + half, j3 = j + 6 + half;
            int s0 = sSrc[j0], s1 = sSrc[j1], s2 = sSrc[j2], s3 = sSrc[j3];
            uint2 h0 = *(const uint2*)(Hu + (size_t)(s0 * 4 + b) * 64 + cc * 2);
            uint2 h1 = *(const uint2*)(Hu + (size_t)(s1 * 4 + b) * 64 + cc * 2);
            uint2 h2 = *(const uint2*)(Hu + (size_t)(s2 * 4 + b) * 64 + cc * 2);
            uint2 h3 = *(const uint2*)(Hu + (size_t)(s3 * 4 + b) * 64 + cc * 2);
            float al0 = sAe[j0 * 4 + b], al1 = sAe[j1 * 4 + b];
            float al2 = sAe[j2 * 4 + b], al3 = sAe[j3 * 4 + b];
            a0 += al0 * bflo(h0.x) + al1 * bflo(h1.x) + al2 * bflo(h2.x) + al3 * bflo(h3.x);
            a1 += al0 * bfhi(h0.x) + al1 * bfhi(h1.x) + al2 * bfhi(h2.x) + al3 * bfhi(h3.x);
            a2 += al0 * bflo(h0.y) + al1 * bflo(h1.y) + al2 * bflo(h2.y) + al3 * bflo(h3.y);
            a3 += al0 * bfhi(h0.y) + al1 * bfhi(h1.y) + al2 * bfhi(h2.y) + al3 * bfhi(h3.y);
        }
        for (; j < cnt; j += 2) {
            int jj = j + half;
            bool valid = jj < cnt;
            int sj = sSrc[valid ? jj : j];
            float al = valid ? sAe[jj * 4 + b] : 0.f;
            uint2 hv = *(const uint2*)(Hu + (size_t)(sj * 4 + b) * 64 + cc * 2);
            a0 += al * bflo(hv.x); a1 += al * bfhi(hv.x);
            a2 += al * bflo(hv.y); a3 += al * bfhi(hv.y);
        }
        a0 += __shfl_xor(a0, 32); a1 += __shfl_xor(a1, 32);
        a2 += __shfl_xor(a2, 32); a3 += __shfl_xor(a3, 32);
        if (half == 0) {
            int d0 = cc * 4;
            float o0 = fmaxf(a0 + bias[d0],     0.f);
            float o1 = fmaxf(a1 + bias[d0 + 1], 0.f);
            float o2 = fmaxf(a2 + bias[d0 + 2], 0.f);
            float o3 = fmaxf(a3 + bias[d0 + 3], 0.f);
            if (addNext) {
                float st = state[b * N_NODES + n];
                o0 += st * wnsN[d0]     + bnsN[d0];
                o1 += st * wnsN[d0 + 1] + bnsN[d0 + 1];
                o2 += st * wnsN[d0 + 2] + bnsN[d0 + 2];
                o3 += st * wnsN[d0 + 3] + bnsN[d0 + 3];
            }
            unsigned wlo2 = (unsigned)f2bf(o0) | ((unsigned)f2bf(o1) << 16);
            unsigned whi2 = (unsigned)f2bf(o2) | ((unsigned)f2bf(o3) << 16);
            *(uint2*)((unsigned*)Xout + (size_t)(n * 4 + b) * 64 + cc * 2) = make_uint2(wlo2, whi2);
        }
    } else {
        // 3-pass fallback (rare; block-uniform)
        float m = -1e30f;
        for (int i = start + t; i < end; i += 64) {
            int sn = srcLst[i];
            float v = aSrcP[sn * 4 + b] + adst;
            m = fmaxf(m, v > 0.f ? v : SLOPE * v);
        }
        m = fmaxf(m, __shfl_xor(m, 1));  m = fmaxf(m, __shfl_xor(m, 2));
        m = fmaxf(m, __shfl_xor(m, 4));  m = fmaxf(m, __shfl_xor(m, 8));
        m = fmaxf(m, __shfl_xor(m, 16)); m = fmaxf(m, __shfl_xor(m, 32));
        float s = 0.f;
        for (int i = start + t; i < end; i += 64) {
            int sn = srcLst[i];
            float v = aSrcP[sn * 4 + b] + adst;
            float ae2 = v > 0.f ? v : SLOPE * v;
            s += __expf(ae2 - m);
        }
        s += __shfl_xor(s, 1);  s += __shfl_xor(s, 2);  s += __shfl_xor(s, 4);
        s += __shfl_xor(s, 8);  s += __shfl_xor(s, 16); s += __shfl_xor(s, 32);
        float inv = 1.f / s;
        float accx = 0.f, accy = 0.f;
        for (int c0 = start; c0 < end; c0 += 64) {
            int c = min(64, end - c0);
            if (t < c) {
                int sn = srcLst[c0 + t];
                if (b == 0) sSrc[t] = sn;
                float v = aSrcP[sn * 4 + b] + adst;
                float ae2 = v > 0.f ? v : SLOPE * v;
                sAe[t * 4 + b] = __expf(ae2 - m);
            }
            __syncthreads();
            for (int j = 0; j < c; j++) {
                float a0 = sAe[j * 4 + b];
                unsigned h0 = Hu[(size_t)(sSrc[j] * 4 + b) * 64 + t];
                accx += a0 * bflo(h0);
                accy += a0 * bfhi(h0);
            }
            __syncthreads();
        }
        float ox = fmaxf(accx * inv + bias[2 * t], 0.f);
        float oy = fmaxf(accy * inv + bias[2 * t + 1], 0.f);
        if (addNext) {
            float st = state[b * N_NODES + n];
            ox += st * wnsN[2 * t]     + bnsN[2 * t];
            oy += st * wnsN[2 * t + 1] + bnsN[2 * t + 1];
        }
        ((unsigned*)Xout)[(size_t)(n * 4 + b) * 64 + t] =
            (unsigned)f2bf(ox) | ((unsigned)f2bf(oy) << 16);
    }
}

// ---------------- head ----------------

__global__ __launch_bounds__(128) void sum_nodes_kernel(const unsigned short* __restrict__ X, float* state_emb) {
    int cx = blockIdx.x, b = blockIdx.y, d = threadIdx.x;
    int n0 = cx * 157, n1 = n0 + 157;
    if (n1 > N_NODES) n1 = N_NODES;
    float acc = 0.f;
    for (int n = n0; n < n1; n++) acc += bf2f(X[(size_t)(n * 4 + b) * 128 + d]);
    atomicAdd(&state_emb[b * 128 + d], acc);
}

// ---------------- final: out = relu(X3@W2+b2).W3[128:] + c1[b] + b3 ; c1 computed inline ----------------

__global__ __launch_bounds__(256) void final_mfma(
    const unsigned short* __restrict__ X,
    const unsigned short* __restrict__ WThi, const unsigned short* __restrict__ WTlo,
    const float* __restrict__ b2, const float* __restrict__ W3,
    const float* __restrict__ b3,
    const float* __restrict__ state_emb, const float* __restrict__ W1,
    const float* __restrict__ b1,
    float* __restrict__ out)
{
    __shared__ float sB2[128], sW3[128];
    __shared__ float sPart[64 * 4];
    __shared__ float sC1p[8], sC1[4];

    int tid = threadIdx.x;
    int g0 = blockIdx.x * 64;
    int w = tid >> 6, lane = tid & 63;
    int quad = lane >> 4, mcol = lane & 15;

    if (tid < 128) { sB2[tid] = b2[tid]; sW3[tid] = W3[128 + tid]; }

    // inline c1[b] = relu(state_emb[b]@W1 + b1) . W3[0:128]  (redundant per block; removes a serial kernel)
    {
        int d = tid & 127;
        int bh = tid >> 7;   // half 0: b={0,2}; half 1: b={1,3}
        float p0 = b1[d], p1 = b1[d];
        for (int k = 0; k < 128; k++) {
            float wv = W1[k * 128 + d];
            p0 += state_emb[bh * 128 + k] * wv;
            p1 += state_emb[(bh + 2) * 128 + k] * wv;
        }
        float w3d = W3[d];
        p0 = fmaxf(p0, 0.f) * w3d;
        p1 = fmaxf(p1, 0.f) * w3d;
#pragma unroll
        for (int off = 1; off < 64; off <<= 1) {
            p0 += __shfl_xor(p0, off);
            p1 += __shfl_xor(p1, off);
        }
        if (lane == 0) { sC1p[w * 2 + 0] = p0; sC1p[w * 2 + 1] = p1; }
    }
    __syncthreads();
    if (tid == 0) {
        sC1[0] = sC1p[0] + sC1p[2];  sC1[2] = sC1p[1] + sC1p[3];
        sC1[1] = sC1p[4] + sC1p[6];  sC1[3] = sC1p[5] + sC1p[7];
    }

    float4v acc[4][2];
#pragma unroll
    for (int mt = 0; mt < 4; mt++)
#pragma unroll
        for (int nt = 0; nt < 2; nt++) acc[mt][nt] = (float4v){0.f, 0.f, 0.f, 0.f};

#pragma unroll 1
    for (int term = 0; term < 2; term++) {
        const unsigned short* WT = term ? WTlo : WThi;
        short8 Bf[4][2];
#pragma unroll
        for (int kc = 0; kc < 4; kc++)
#pragma unroll
            for (int nt = 0; nt < 2; nt++)
                Bf[kc][nt] = *(const short8*)(WT + (w * 32 + nt * 16 + mcol) * 128 + kc * 32 + quad * 8);
#pragma unroll
        for (int kc = 0; kc < 4; kc++) {
            short8 Aa[4];
#pragma unroll
            for (int mt = 0; mt < 4; mt++)
                Aa[mt] = *(const short8*)(X + (size_t)(g0 + mt * 16 + mcol) * 128 + kc * 32 + quad * 8);
#pragma unroll
            for (int mt = 0; mt < 4; mt++)
#pragma unroll
                for (int nt = 0; nt < 2; nt++)
                    acc[mt][nt] = __builtin_amdgcn_mfma_f32_16x16x32_bf16(Aa[mt], Bf[kc][nt], acc[mt][nt], 0, 0, 0);
        }
    }

    float pp[16];
#pragma unroll
    for (int r16 = 0; r16 < 16; r16++) pp[r16] = 0.f;
#pragma unroll
    for (int mt = 0; mt < 4; mt++)
#pragma unroll
        for (int nt = 0; nt < 2; nt++)
#pragma unroll
            for (int reg = 0; reg < 4; reg++) {
                int col = w * 32 + nt * 16 + mcol;
                float v = acc[mt][nt][reg] + sB2[col];
                v = v > 0.f ? v : 0.f;
                pp[mt * 4 + reg] += v * sW3[col];
            }
#pragma unroll
    for (int off = 1; off < 16; off <<= 1)
#pragma unroll
        for (int r16 = 0; r16 < 16; r16++)
            pp[r16] += __shfl_xor(pp[r16], off);
    if (mcol == 0) {
#pragma unroll
        for (int r16 = 0; r16 < 16; r16++) {
            int row = (r16 >> 2) * 16 + quad * 4 + (r16 & 3);
            sPart[row * 4 + w] = pp[r16];
        }
    }
    __syncthreads();
    if (tid < 64) {
        float p = sPart[tid * 4] + sPart[tid * 4 + 1] + sPart[tid * 4 + 2] + sPart[tid * 4 + 3];
        int g = g0 + tid;
        out[(g & 3) * N_NODES + (g >> 2)] = p + sC1[g & 3] + b3[0];
    }
}

// ---------------- launch ----------------

extern "C" void kernel_launch(void* const* d_in, const int* in_sizes, int n_in,
                              void* d_out, int out_size, void* d_ws, size_t ws_size,
                              hipStream_t stream) {
    const float* state    = (const float*)d_in[0];   // [B,N]
    const float* strucEmb = (const float*)d_in[1];   // [N,128]
    const int*   edge_idx = (const int*)d_in[2];     // [2,Etot]
    const float* gat_W    = (const float*)d_in[3];   // [3,128,128]
    const float* gat_aS   = (const float*)d_in[4];
    const float* gat_aD   = (const float*)d_in[5];
    const float* gat_Wns  = (const float*)d_in[6];
    const float* gat_bns  = (const float*)d_in[7];
    const float* gat_bias = (const float*)d_in[8];
    const float* W1 = (const float*)d_in[9];
    const float* b1 = (const float*)d_in[10];
    const float* W2 = (const float*)d_in[11];
    const float* b2 = (const float*)d_in[12];
    const float* W3 = (const float*)d_in[13];
    const float* b3 = (const float*)d_in[14];
    float* out = (float*)d_out;

    int Etot = in_sizes[2] / 2;
    const int* srcArr = edge_idx;
    const int* dstArr = edge_idx + Etot;

    float* ws = (float*)d_ws;
    unsigned short* Xb = (unsigned short*)ws;              // 5,120,000 us
    unsigned short* Hb = (unsigned short*)(ws + 2560000);  // 5,120,000 us
    float* aSrcP       = ws + 5120000;                     // 40,000 f
    float* aDstP       = ws + 5160000;                     // 40,000 f
    float* state_emb   = ws + 5200000;                     // 512 f
    unsigned short* whi = (unsigned short*)(ws + 5200516); // 65,536 us
    unsigned short* wlo = whi + 4 * 16384;                 // 65,536 us
    int*   iws         = (int*)(ws + 5200516 + 65536);
    int*   rowOff      = iws;                              // N+1
    int*   deg         = iws + 10001;
    int*   cursor      = deg + 10000;
    int*   srcLst      = cursor + 10000;                   // Etot

    setup_kernel<<<20296, 256, 0, stream>>>(strucEmb, state, gat_Wns, gat_bns,
                                            gat_W, W2, Xb, whi, wlo, deg, cursor, state_emb);
    hist_kernel<<<(Etot + 255) / 256, 256, 0, stream>>>(dstArr, Etot, deg);
    scan_kernel<<<1, 1024, 0, stream>>>(deg, rowOff);
    scatter_kernel<<<(Etot + 255) / 256, 256, 0, stream>>>(srcArr, dstArr, Etot, rowOff, cursor, srcLst);

    for (int l = 0; l < 3; l++) {
        gemm_att_mfma<<<BN / 64, 256, 0, stream>>>(
            Xb, whi + (size_t)l * 16384, wlo + (size_t)l * 16384,
            gat_aS + l * 128, gat_aD + l * 128, Hb, aSrcP, aDstP);
        sm_agg_kernel<<<N_NODES, 256, 0, stream>>>(
            rowOff, srcLst, aSrcP, aDstP, Hb, gat_bias + l * 128,
            state, gat_Wns + (l + 1 < 3 ? (l + 1) * 128 : 0),
            gat_bns + (l + 1 < 3 ? (l + 1) * 128 : 0), (l < 2) ? 1 : 0, Xb);
    }

    sum_nodes_kernel<<<dim3(64, B_SZ), 128, 0, stream>>>(Xb, state_emb);
    final_mfma<<<BN / 64, 256, 0, stream>>>(Xb, whi + 3 * 16384, wlo + 3 * 16384,
                                            b2, W3, b3, state_emb, W1, b1, out);
}

// Round 8
// 332.112 us; speedup vs baseline: 2.2667x; 1.0157x over previous
//
#include <hip/hip_runtime.h>
#include <math.h>

#define N_NODES 10000
#define B_SZ 4
#define SLOPE 0.01f
#define BN (B_SZ * N_NODES)
#define PADK 136   // ushorts per LDS C-row (272B, 16B-aligned)

typedef __attribute__((ext_vector_type(8))) short short8;
typedef __attribute__((ext_vector_type(4))) float float4v;

__device__ __forceinline__ unsigned short f2bf(float f) {
    unsigned u = __builtin_bit_cast(unsigned, f);
    u += 0x7fffu + ((u >> 16) & 1u);   // RNE
    return (unsigned short)(u >> 16);
}
__device__ __forceinline__ float bf2f(unsigned short s) {
    unsigned u = ((unsigned)s) << 16;
    return __builtin_bit_cast(float, u);
}
__device__ __forceinline__ float bflo(unsigned u) { return __builtin_bit_cast(float, u << 16); }
__device__ __forceinline__ float bfhi(unsigned u) { return __builtin_bit_cast(float, u & 0xffff0000u); }

// ---------------- fused setup: prep0 + wconv + init ----------------

__global__ __launch_bounds__(256) void setup_kernel(
    const float* __restrict__ strucEmb, const float* __restrict__ state,
    const float* __restrict__ Wns0, const float* __restrict__ bns0,
    const float* __restrict__ gatW, const float* __restrict__ W2,
    unsigned short* __restrict__ XS,
    unsigned short* __restrict__ whi, unsigned short* __restrict__ wlo,
    int* deg, int* cursor, float* state_emb)
{
    int bx = blockIdx.x, tid = threadIdx.x;
    if (bx < 20000) {
        int idx = bx * 256 + tid;
        int g = idx >> 7, d = idx & 127;
        int n = g >> 2, b = g & 3;
        float v = strucEmb[(size_t)n * 128 + d] + state[b * N_NODES + n] * Wns0[d] + bns0[d];
        XS[idx] = f2bf(v);
    } else if (bx < 20256) {
        int i = (bx - 20000) * 256 + tid;     // 0..65535
        int w = i >> 14, rem = i & 16383;
        int k = rem >> 7, c = rem & 127;
        const float* src = (w < 3) ? (gatW + (size_t)w * 16384) : W2;
        float v = src[k * 128 + c];
        unsigned short h = f2bf(v);
        whi[w * 16384 + c * 128 + k] = h;
        wlo[w * 16384 + c * 128 + k] = f2bf(v - bf2f(h));
    } else {
        int i = (bx - 20256) * 256 + tid;
        if (i < N_NODES) { deg[i] = 0; cursor[i] = 0; }
        if (i < 512) state_emb[i] = 0.f;
    }
}

// ---------------- CSR build ----------------

__global__ __launch_bounds__(256) void hist_kernel(const int* __restrict__ dst, int Etot, int* deg) {
    int e = blockIdx.x * 256 + threadIdx.x;
    if (e < Etot) atomicAdd(&deg[dst[e]], 1);
}

__global__ __launch_bounds__(1024) void scan_kernel(const int* __restrict__ deg, int* __restrict__ rowOff) {
    __shared__ int wsum[16];
    int tid = threadIdx.x;
    int lane = tid & 63, wid = tid >> 6;
    int base = tid * 10;
    int v[10]; int tot = 0;
#pragma unroll
    for (int j = 0; j < 10; j++) {
        int idx = base + j;
        int d = (idx < N_NODES) ? deg[idx] : 0;
        tot += d; v[j] = tot;
    }
    int incl = tot;
    for (int off = 1; off < 64; off <<= 1) {
        int t = __shfl_up(incl, off, 64);
        if (lane >= off) incl += t;
    }
    if (lane == 63) wsum[wid] = incl;
    __syncthreads();
    if (wid == 0) {
        int wv = (lane < 16) ? wsum[lane] : 0;
        for (int off = 1; off < 16; off <<= 1) {
            int t = __shfl_up(wv, off, 64);
            if (lane >= off) wv += t;
        }
        if (lane < 16) wsum[lane] = wv;
    }
    __syncthreads();
    int waveoff = (wid > 0) ? wsum[wid - 1] : 0;
    int excl = waveoff + incl - tot;
    if (tid == 0) rowOff[0] = 0;
#pragma unroll
    for (int j = 0; j < 10; j++) {
        int idx = base + j;
        if (idx < N_NODES) rowOff[idx + 1] = excl + v[j];
    }
}

__global__ __launch_bounds__(256) void scatter_kernel(const int* __restrict__ src, const int* __restrict__ dst,
                                                      int Etot, const int* __restrict__ rowOff,
                                                      int* cursor, int* __restrict__ srcLst) {
    int e = blockIdx.x * 256 + threadIdx.x;
    if (e < Etot) {
        int d = dst[e];
        int pos = rowOff[d] + atomicAdd(&cursor[d], 1);
        srcLst[pos] = src[e];
    }
}

// ---------------- MFMA GEMM (GAT layer): H(bf16) = XS(bf16) @ W ; att dots ----------------

__global__ __launch_bounds__(256) void gemm_att_mfma(
    const unsigned short* __restrict__ XS,
    const unsigned short* __restrict__ WThi, const unsigned short* __restrict__ WTlo,
    const float* __restrict__ attS, const float* __restrict__ attD,
    unsigned short* __restrict__ Hout, float* __restrict__ aSrcP, float* __restrict__ aDstP)
{
    __shared__ __align__(16) unsigned short sCus[64 * PADK];
    __shared__ float sAs[128], sAd[128];
    __shared__ float sPart[64 * 8];

    int tid = threadIdx.x;
    int g0 = blockIdx.x * 64;
    int w = tid >> 6, lane = tid & 63;
    int quad = lane >> 4, mcol = lane & 15;

    if (tid < 128) { sAs[tid] = attS[tid]; sAd[tid] = attD[tid]; }

    float4v acc[4][2];
#pragma unroll
    for (int mt = 0; mt < 4; mt++)
#pragma unroll
        for (int nt = 0; nt < 2; nt++) acc[mt][nt] = (float4v){0.f, 0.f, 0.f, 0.f};

#pragma unroll 1
    for (int term = 0; term < 2; term++) {
        const unsigned short* WT = term ? WTlo : WThi;
        short8 Bf[4][2];
#pragma unroll
        for (int kc = 0; kc < 4; kc++)
#pragma unroll
            for (int nt = 0; nt < 2; nt++)
                Bf[kc][nt] = *(const short8*)(WT + (w * 32 + nt * 16 + mcol) * 128 + kc * 32 + quad * 8);
#pragma unroll
        for (int kc = 0; kc < 4; kc++) {
            short8 Aa[4];
#pragma unroll
            for (int mt = 0; mt < 4; mt++)
                Aa[mt] = *(const short8*)(XS + (size_t)(g0 + mt * 16 + mcol) * 128 + kc * 32 + quad * 8);
#pragma unroll
            for (int mt = 0; mt < 4; mt++)
#pragma unroll
                for (int nt = 0; nt < 2; nt++)
                    acc[mt][nt] = __builtin_amdgcn_mfma_f32_16x16x32_bf16(Aa[mt], Bf[kc][nt], acc[mt][nt], 0, 0, 0);
        }
    }

    __syncthreads();   // sAs/sAd visible

    float pp[16], pd[16];
#pragma unroll
    for (int r16 = 0; r16 < 16; r16++) { pp[r16] = 0.f; pd[r16] = 0.f; }
#pragma unroll
    for (int mt = 0; mt < 4; mt++)
#pragma unroll
        for (int nt = 0; nt < 2; nt++)
#pragma unroll
            for (int reg = 0; reg < 4; reg++) {
                int row = mt * 16 + quad * 4 + reg;   // C/D: col=lane&15, row=quad*4+reg
                int col = w * 32 + nt * 16 + mcol;
                float v = acc[mt][nt][reg];
                sCus[row * PADK + col] = f2bf(v);
                pp[mt * 4 + reg] += v * sAs[col];
                pd[mt * 4 + reg] += v * sAd[col];
            }
#pragma unroll
    for (int off = 1; off < 16; off <<= 1)
#pragma unroll
        for (int r16 = 0; r16 < 16; r16++) {
            pp[r16] += __shfl_xor(pp[r16], off);
            pd[r16] += __shfl_xor(pd[r16], off);
        }
    if (mcol == 0) {
#pragma unroll
        for (int r16 = 0; r16 < 16; r16++) {
            int row = (r16 >> 2) * 16 + quad * 4 + (r16 & 3);
            sPart[row * 8 + w * 2 + 0] = pp[r16];
            sPart[row * 8 + w * 2 + 1] = pd[r16];
        }
    }
    __syncthreads();

    for (int i = tid; i < 64 * 16; i += 256) {
        int r = i >> 4, c8 = i & 15;
        uint4 u = *(uint4*)(sCus + r * PADK + c8 * 8);
        *(uint4*)(Hout + (size_t)(g0 + r) * 128 + c8 * 8) = u;
    }
    if (tid < 64) {
        float s0 = sPart[tid * 8] + sPart[tid * 8 + 2] + sPart[tid * 8 + 4] + sPart[tid * 8 + 6];
        float s1 = sPart[tid * 8 + 1] + sPart[tid * 8 + 3] + sPart[tid * 8 + 5] + sPart[tid * 8 + 7];
        aSrcP[g0 + tid] = s0;
        aDstP[g0 + tid] = s1;
    }
}

// ---------------- fused softmax + aggregate (+ next-layer Wns/bns), bf16 in/out ----------------
// One block per node; wave b = batch b. ALL LDS is per-wave -> zero barriers.
// Gather: lane = (edge-sub 0..3, col16 0..15); uint4 (16B) loads, 4 in flight.

__global__ __launch_bounds__(256) void sm_agg_kernel(
    const int* __restrict__ rowOff, const int* __restrict__ srcLst,
    const float* __restrict__ aSrcP, const float* __restrict__ aDstP,
    const unsigned short* __restrict__ H,
    const float* __restrict__ bias,
    const float* __restrict__ state, const float* __restrict__ wnsN,
    const float* __restrict__ bnsN, int addNext,
    unsigned short* __restrict__ Xout)
{
    __shared__ int   sSrcB[4 * 64];
    __shared__ float sAeB[4 * 64];
    int n = blockIdx.x;
    int start = rowOff[n], end = rowOff[n + 1];
    int cnt = end - start;
    int tid = threadIdx.x;
    int b = tid >> 6, t = tid & 63;
    float adst = aDstP[n * 4 + b];
    int*   sSrc = sSrcB + b * 64;
    float* sAe  = sAeB + b * 64;
    const uint4* H4 = (const uint4*)H;   // 16 uint4 per 128-bf16 row

    if (cnt <= 64) {
        float ae = -1e30f;
        if (t < cnt) {
            int sn = srcLst[start + t];
            sSrc[t] = sn;
            float v = aSrcP[sn * 4 + b] + adst;
            ae = v > 0.f ? v : SLOPE * v;
        }
        float m = ae;
        m = fmaxf(m, __shfl_xor(m, 1));  m = fmaxf(m, __shfl_xor(m, 2));
        m = fmaxf(m, __shfl_xor(m, 4));  m = fmaxf(m, __shfl_xor(m, 8));
        m = fmaxf(m, __shfl_xor(m, 16)); m = fmaxf(m, __shfl_xor(m, 32));
        float e = (t < cnt) ? __expf(ae - m) : 0.f;
        float s = e;
        s += __shfl_xor(s, 1);  s += __shfl_xor(s, 2);  s += __shfl_xor(s, 4);
        s += __shfl_xor(s, 8);  s += __shfl_xor(s, 16); s += __shfl_xor(s, 32);
        float inv = 1.f / s;
        if (t < cnt) sAe[t] = e * inv;
        int cntE = (cnt + 3) & ~3;
        if (t >= cnt && t < cntE) { sSrc[t] = n; sAe[t] = 0.f; }  // zero-alpha pad

        int esub = t >> 4, c16 = t & 15;
        float a0 = 0.f, a1 = 0.f, a2 = 0.f, a3 = 0.f, a4 = 0.f, a5 = 0.f, a6 = 0.f, a7 = 0.f;
        int j = 0;
        for (; j + 16 <= cntE; j += 16) {
            uint4 h[4]; float al[4];
#pragma unroll
            for (int r = 0; r < 4; r++) {
                int jj = j + r * 4 + esub;
                h[r] = H4[(size_t)(sSrc[jj] * 4 + b) * 16 + c16];
                al[r] = sAe[jj];
            }
#pragma unroll
            for (int r = 0; r < 4; r++) {
                a0 += al[r] * bflo(h[r].x); a1 += al[r] * bfhi(h[r].x);
                a2 += al[r] * bflo(h[r].y); a3 += al[r] * bfhi(h[r].y);
                a4 += al[r] * bflo(h[r].z); a5 += al[r] * bfhi(h[r].z);
                a6 += al[r] * bflo(h[r].w); a7 += al[r] * bfhi(h[r].w);
            }
        }
        for (; j < cntE; j += 4) {
            int jj = j + esub;
            uint4 hv = H4[(size_t)(sSrc[jj] * 4 + b) * 16 + c16];
            float al = sAe[jj];
            a0 += al * bflo(hv.x); a1 += al * bfhi(hv.x);
            a2 += al * bflo(hv.y); a3 += al * bfhi(hv.y);
            a4 += al * bflo(hv.z); a5 += al * bfhi(hv.z);
            a6 += al * bflo(hv.w); a7 += al * bfhi(hv.w);
        }
        a0 += __shfl_xor(a0, 16); a1 += __shfl_xor(a1, 16);
        a2 += __shfl_xor(a2, 16); a3 += __shfl_xor(a3, 16);
        a4 += __shfl_xor(a4, 16); a5 += __shfl_xor(a5, 16);
        a6 += __shfl_xor(a6, 16); a7 += __shfl_xor(a7, 16);
        a0 += __shfl_xor(a0, 32); a1 += __shfl_xor(a1, 32);
        a2 += __shfl_xor(a2, 32); a3 += __shfl_xor(a3, 32);
        a4 += __shfl_xor(a4, 32); a5 += __shfl_xor(a5, 32);
        a6 += __shfl_xor(a6, 32); a7 += __shfl_xor(a7, 32);
        if (esub == 0) {
            int d0 = c16 * 8;
            float o0 = fmaxf(a0 + bias[d0],     0.f);
            float o1 = fmaxf(a1 + bias[d0 + 1], 0.f);
            float o2 = fmaxf(a2 + bias[d0 + 2], 0.f);
            float o3 = fmaxf(a3 + bias[d0 + 3], 0.f);
            float o4 = fmaxf(a4 + bias[d0 + 4], 0.f);
            float o5 = fmaxf(a5 + bias[d0 + 5], 0.f);
            float o6 = fmaxf(a6 + bias[d0 + 6], 0.f);
            float o7 = fmaxf(a7 + bias[d0 + 7], 0.f);
            if (addNext) {
                float st = state[b * N_NODES + n];
                o0 += st * wnsN[d0]     + bnsN[d0];
                o1 += st * wnsN[d0 + 1] + bnsN[d0 + 1];
                o2 += st * wnsN[d0 + 2] + bnsN[d0 + 2];
                o3 += st * wnsN[d0 + 3] + bnsN[d0 + 3];
                o4 += st * wnsN[d0 + 4] + bnsN[d0 + 4];
                o5 += st * wnsN[d0 + 5] + bnsN[d0 + 5];
                o6 += st * wnsN[d0 + 6] + bnsN[d0 + 6];
                o7 += st * wnsN[d0 + 7] + bnsN[d0 + 7];
            }
            uint4 u;
            u.x = (unsigned)f2bf(o0) | ((unsigned)f2bf(o1) << 16);
            u.y = (unsigned)f2bf(o2) | ((unsigned)f2bf(o3) << 16);
            u.z = (unsigned)f2bf(o4) | ((unsigned)f2bf(o5) << 16);
            u.w = (unsigned)f2bf(o6) | ((unsigned)f2bf(o7) << 16);
            ((uint4*)Xout)[(size_t)(n * 4 + b) * 16 + c16] = u;
        }
    } else {
        // fallback (deg > 64, vanishingly rare) — per-wave chunks, no barriers
        const unsigned* Hu = (const unsigned*)H;
        float m = -1e30f;
        for (int i = start + t; i < end; i += 64) {
            int sn = srcLst[i];
            float v = aSrcP[sn * 4 + b] + adst;
            m = fmaxf(m, v > 0.f ? v : SLOPE * v);
        }
        m = fmaxf(m, __shfl_xor(m, 1));  m = fmaxf(m, __shfl_xor(m, 2));
        m = fmaxf(m, __shfl_xor(m, 4));  m = fmaxf(m, __shfl_xor(m, 8));
        m = fmaxf(m, __shfl_xor(m, 16)); m = fmaxf(m, __shfl_xor(m, 32));
        float s = 0.f;
        for (int i = start + t; i < end; i += 64) {
            int sn = srcLst[i];
            float v = aSrcP[sn * 4 + b] + adst;
            float ae2 = v > 0.f ? v : SLOPE * v;
            s += __expf(ae2 - m);
        }
        s += __shfl_xor(s, 1);  s += __shfl_xor(s, 2);  s += __shfl_xor(s, 4);
        s += __shfl_xor(s, 8);  s += __shfl_xor(s, 16); s += __shfl_xor(s, 32);
        float inv = 1.f / s;
        float accx = 0.f, accy = 0.f;
        for (int c0 = start; c0 < end; c0 += 64) {
            int c = min(64, end - c0);
            if (t < c) {
                int sn = srcLst[c0 + t];
                sSrc[t] = sn;
                float v = aSrcP[sn * 4 + b] + adst;
                float ae2 = v > 0.f ? v : SLOPE * v;
                sAe[t] = __expf(ae2 - m);
            }
            for (int j = 0; j < c; j++) {
                float a0 = sAe[j];
                unsigned h0 = Hu[(size_t)(sSrc[j] * 4 + b) * 64 + t];
                accx += a0 * bflo(h0);
                accy += a0 * bfhi(h0);
            }
        }
        float ox = fmaxf(accx * inv + bias[2 * t], 0.f);
        float oy = fmaxf(accy * inv + bias[2 * t + 1], 0.f);
        if (addNext) {
            float st = state[b * N_NODES + n];
            ox += st * wnsN[2 * t]     + bnsN[2 * t];
            oy += st * wnsN[2 * t + 1] + bnsN[2 * t + 1];
        }
        ((unsigned*)Xout)[(size_t)(n * 4 + b) * 64 + t] =
            (unsigned)f2bf(ox) | ((unsigned)f2bf(oy) << 16);
    }
}

// ---------------- head ----------------

__global__ __launch_bounds__(128) void sum_nodes_kernel(const unsigned short* __restrict__ X, float* state_emb) {
    int cx = blockIdx.x, b = blockIdx.y, d = threadIdx.x;
    int n0 = cx * 157, n1 = n0 + 157;
    if (n1 > N_NODES) n1 = N_NODES;
    float acc = 0.f;
    for (int n = n0; n < n1; n++) acc += bf2f(X[(size_t)(n * 4 + b) * 128 + d]);
    atomicAdd(&state_emb[b * 128 + d], acc);
}

// ---------------- final: out = relu(X3@W2+b2).W3[128:] + c1[b] + b3 ; c1 inline ----------------

__global__ __launch_bounds__(256) void final_mfma(
    const unsigned short* __restrict__ X,
    const unsigned short* __restrict__ WThi, const unsigned short* __restrict__ WTlo,
    const float* __restrict__ b2, const float* __restrict__ W3,
    const float* __restrict__ b3,
    const float* __restrict__ state_emb, const float* __restrict__ W1,
    const float* __restrict__ b1,
    float* __restrict__ out)
{
    __shared__ float sB2[128], sW3[128];
    __shared__ float sPart[64 * 4];
    __shared__ float sC1p[8], sC1[4];

    int tid = threadIdx.x;
    int g0 = blockIdx.x * 64;
    int w = tid >> 6, lane = tid & 63;
    int quad = lane >> 4, mcol = lane & 15;

    if (tid < 128) { sB2[tid] = b2[tid]; sW3[tid] = W3[128 + tid]; }

    {
        int d = tid & 127;
        int bh = tid >> 7;   // half 0: b={0,2}; half 1: b={1,3}
        float p0 = b1[d], p1 = b1[d];
        for (int k = 0; k < 128; k++) {
            float wv = W1[k * 128 + d];
            p0 += state_emb[bh * 128 + k] * wv;
            p1 += state_emb[(bh + 2) * 128 + k] * wv;
        }
        float w3d = W3[d];
        p0 = fmaxf(p0, 0.f) * w3d;
        p1 = fmaxf(p1, 0.f) * w3d;
#pragma unroll
        for (int off = 1; off < 64; off <<= 1) {
            p0 += __shfl_xor(p0, off);
            p1 += __shfl_xor(p1, off);
        }
        if (lane == 0) { sC1p[w * 2 + 0] = p0; sC1p[w * 2 + 1] = p1; }
    }
    __syncthreads();
    if (tid == 0) {
        sC1[0] = sC1p[0] + sC1p[2];  sC1[2] = sC1p[1] + sC1p[3];
        sC1[1] = sC1p[4] + sC1p[6];  sC1[3] = sC1p[5] + sC1p[7];
    }

    float4v acc[4][2];
#pragma unroll
    for (int mt = 0; mt < 4; mt++)
#pragma unroll
        for (int nt = 0; nt < 2; nt++) acc[mt][nt] = (float4v){0.f, 0.f, 0.f, 0.f};

#pragma unroll 1
    for (int term = 0; term < 2; term++) {
        const unsigned short* WT = term ? WTlo : WThi;
        short8 Bf[4][2];
#pragma unroll
        for (int kc = 0; kc < 4; kc++)
#pragma unroll
            for (int nt = 0; nt < 2; nt++)
                Bf[kc][nt] = *(const short8*)(WT + (w * 32 + nt * 16 + mcol) * 128 + kc * 32 + quad * 8);
#pragma unroll
        for (int kc = 0; kc < 4; kc++) {
            short8 Aa[4];
#pragma unroll
            for (int mt = 0; mt < 4; mt++)
                Aa[mt] = *(const short8*)(X + (size_t)(g0 + mt * 16 + mcol) * 128 + kc * 32 + quad * 8);
#pragma unroll
            for (int mt = 0; mt < 4; mt++)
#pragma unroll
                for (int nt = 0; nt < 2; nt++)
                    acc[mt][nt] = __builtin_amdgcn_mfma_f32_16x16x32_bf16(Aa[mt], Bf[kc][nt], acc[mt][nt], 0, 0, 0);
        }
    }

    float pp[16];
#pragma unroll
    for (int r16 = 0; r16 < 16; r16++) pp[r16] = 0.f;
#pragma unroll
    for (int mt = 0; mt < 4; mt++)
#pragma unroll
        for (int nt = 0; nt < 2; nt++)
#pragma unroll
            for (int reg = 0; reg < 4; reg++) {
                int col = w * 32 + nt * 16 + mcol;
                float v = acc[mt][nt][reg] + sB2[col];
                v = v > 0.f ? v : 0.f;
                pp[mt * 4 + reg] += v * sW3[col];
            }
#pragma unroll
    for (int off = 1; off < 16; off <<= 1)
#pragma unroll
        for (int r16 = 0; r16 < 16; r16++)
            pp[r16] += __shfl_xor(pp[r16], off);
    if (mcol == 0) {
#pragma unroll
        for (int r16 = 0; r16 < 16; r16++) {
            int row = (r16 >> 2) * 16 + quad * 4 + (r16 & 3);
            sPart[row * 4 + w] = pp[r16];
        }
    }
    __syncthreads();
    if (tid < 64) {
        float p = sPart[tid * 4] + sPart[tid * 4 + 1] + sPart[tid * 4 + 2] + sPart[tid * 4 + 3];
        int g = g0 + tid;
        out[(g & 3) * N_NODES + (g >> 2)] = p + sC1[g & 3] + b3[0];
    }
}

// ---------------- launch ----------------

extern "C" void kernel_launch(void* const* d_in, const int* in_sizes, int n_in,
                              void* d_out, int out_size, void* d_ws, size_t ws_size,
                              hipStream_t stream) {
    const float* state    = (const float*)d_in[0];   // [B,N]
    const float* strucEmb = (const float*)d_in[1];   // [N,128]
    const int*   edge_idx = (const int*)d_in[2];     // [2,Etot]
    const float* gat_W    = (const float*)d_in[3];   // [3,128,128]
    const float* gat_aS   = (const float*)d_in[4];
    const float* gat_aD   = (const float*)d_in[5];
    const float* gat_Wns  = (const float*)d_in[6];
    const float* gat_bns  = (const float*)d_in[7];
    const float* gat_bias = (const float*)d_in[8];
    const float* W1 = (const float*)d_in[9];
    const float* b1 = (const float*)d_in[10];
    const float* W2 = (const float*)d_in[11];
    const float* b2 = (const float*)d_in[12];
    const float* W3 = (const float*)d_in[13];
    const float* b3 = (const float*)d_in[14];
    float* out = (float*)d_out;

    int Etot = in_sizes[2] / 2;
    const int* srcArr = edge_idx;
    const int* dstArr = edge_idx + Etot;

    float* ws = (float*)d_ws;
    unsigned short* Xb = (unsigned short*)ws;              // 5,120,000 us
    unsigned short* Hb = (unsigned short*)(ws + 2560000);  // 5,120,000 us
    float* aSrcP       = ws + 5120000;                     // 40,000 f
    float* aDstP       = ws + 5160000;                     // 40,000 f
    float* state_emb   = ws + 5200000;                     // 512 f
    unsigned short* whi = (unsigned short*)(ws + 5200516); // 65,536 us
    unsigned short* wlo = whi + 4 * 16384;                 // 65,536 us
    int*   iws         = (int*)(ws + 5200516 + 65536);
    int*   rowOff      = iws;                              // N+1
    int*   deg         = iws + 10001;
    int*   cursor      = deg + 10000;
    int*   srcLst      = cursor + 10000;                   // Etot

    setup_kernel<<<20296, 256, 0, stream>>>(strucEmb, state, gat_Wns, gat_bns,
                                            gat_W, W2, Xb, whi, wlo, deg, cursor, state_emb);
    hist_kernel<<<(Etot + 255) / 256, 256, 0, stream>>>(dstArr, Etot, deg);
    scan_kernel<<<1, 1024, 0, stream>>>(deg, rowOff);
    scatter_kernel<<<(Etot + 255) / 256, 256, 0, stream>>>(srcArr, dstArr, Etot, rowOff, cursor, srcLst);

    for (int l = 0; l < 3; l++) {
        gemm_att_mfma<<<BN / 64, 256, 0, stream>>>(
            Xb, whi + (size_t)l * 16384, wlo + (size_t)l * 16384,
            gat_aS + l * 128, gat_aD + l * 128, Hb, aSrcP, aDstP);
        sm_agg_kernel<<<N_NODES, 256, 0, stream>>>(
            rowOff, srcLst, aSrcP, aDstP, Hb, gat_bias + l * 128,
            state, gat_Wns + (l + 1 < 3 ? (l + 1) * 128 : 0),
            gat_bns + (l + 1 < 3 ? (l + 1) * 128 : 0), (l < 2) ? 1 : 0, Xb);
    }

    sum_nodes_kernel<<<dim3(64, B_SZ), 128, 0, stream>>>(Xb, state_emb);
    final_mfma<<<BN / 64, 256, 0, stream>>>(Xb, whi + 3 * 16384, wlo + 3 * 16384,
                                            b2, W3, b3, state_emb, W1, b1, out);
}

// Round 9
// 328.307 us; speedup vs baseline: 2.2929x; 1.0116x over previous
//
#include <hip/hip_runtime.h>
#include <math.h>

#define N_NODES 10000
#define B_SZ 4
#define SLOPE 0.01f
#define BN (B_SZ * N_NODES)
#define PADK 136   // ushorts per LDS C-row (272B, 16B-aligned)

typedef __attribute__((ext_vector_type(8))) short short8;
typedef __attribute__((ext_vector_type(4))) float float4v;

__device__ __forceinline__ unsigned short f2bf(float f) {
    unsigned u = __builtin_bit_cast(unsigned, f);
    u += 0x7fffu + ((u >> 16) & 1u);   // RNE
    return (unsigned short)(u >> 16);
}
__device__ __forceinline__ float bf2f(unsigned short s) {
    unsigned u = ((unsigned)s) << 16;
    return __builtin_bit_cast(float, u);
}
__device__ __forceinline__ float bflo(unsigned u) { return __builtin_bit_cast(float, u << 16); }
__device__ __forceinline__ float bfhi(unsigned u) { return __builtin_bit_cast(float, u & 0xffff0000u); }

// All activations batch-major: row index g = b*N_NODES + n.

// ---------------- fused setup: prep0 + wconv + init ----------------

__global__ __launch_bounds__(256) void setup_kernel(
    const float* __restrict__ strucEmb, const float* __restrict__ state,
    const float* __restrict__ Wns0, const float* __restrict__ bns0,
    const float* __restrict__ gatW, const float* __restrict__ W2,
    unsigned short* __restrict__ XS,
    unsigned short* __restrict__ whi, unsigned short* __restrict__ wlo,
    int* deg, int* cursor, float* state_emb)
{
    int bx = blockIdx.x, tid = threadIdx.x;
    if (bx < 20000) {
        int idx = bx * 256 + tid;
        int g = idx >> 7, d = idx & 127;
        int n = g - (g / N_NODES) * N_NODES;
        float v = strucEmb[(size_t)n * 128 + d] + state[g] * Wns0[d] + bns0[d];
        XS[idx] = f2bf(v);
    } else if (bx < 20256) {
        int i = (bx - 20000) * 256 + tid;     // 0..65535
        int w = i >> 14, rem = i & 16383;
        int k = rem >> 7, c = rem & 127;
        const float* src = (w < 3) ? (gatW + (size_t)w * 16384) : W2;
        float v = src[k * 128 + c];
        unsigned short h = f2bf(v);
        whi[w * 16384 + c * 128 + k] = h;
        wlo[w * 16384 + c * 128 + k] = f2bf(v - bf2f(h));
    } else {
        int i = (bx - 20256) * 256 + tid;
        if (i < N_NODES) { deg[i] = 0; cursor[i] = 0; }
        if (i < 512) state_emb[i] = 0.f;
    }
}

// ---------------- CSR build ----------------

__global__ __launch_bounds__(256) void hist_kernel(const int* __restrict__ dst, int Etot, int* deg) {
    int e = blockIdx.x * 256 + threadIdx.x;
    if (e < Etot) atomicAdd(&deg[dst[e]], 1);
}

__global__ __launch_bounds__(1024) void scan_kernel(const int* __restrict__ deg, int* __restrict__ rowOff) {
    __shared__ int wsum[16];
    int tid = threadIdx.x;
    int lane = tid & 63, wid = tid >> 6;
    int base = tid * 10;
    int v[10]; int tot = 0;
#pragma unroll
    for (int j = 0; j < 10; j++) {
        int idx = base + j;
        int d = (idx < N_NODES) ? deg[idx] : 0;
        tot += d; v[j] = tot;
    }
    int incl = tot;
    for (int off = 1; off < 64; off <<= 1) {
        int t = __shfl_up(incl, off, 64);
        if (lane >= off) incl += t;
    }
    if (lane == 63) wsum[wid] = incl;
    __syncthreads();
    if (wid == 0) {
        int wv = (lane < 16) ? wsum[lane] : 0;
        for (int off = 1; off < 16; off <<= 1) {
            int t = __shfl_up(wv, off, 64);
            if (lane >= off) wv += t;
        }
        if (lane < 16) wsum[lane] = wv;
    }
    __syncthreads();
    int waveoff = (wid > 0) ? wsum[wid - 1] : 0;
    int excl = waveoff + incl - tot;
    if (tid == 0) rowOff[0] = 0;
#pragma unroll
    for (int j = 0; j < 10; j++) {
        int idx = base + j;
        if (idx < N_NODES) rowOff[idx + 1] = excl + v[j];
    }
}

__global__ __launch_bounds__(256) void scatter_kernel(const int* __restrict__ src, const int* __restrict__ dst,
                                                      int Etot, const int* __restrict__ rowOff,
                                                      int* cursor, int* __restrict__ srcLst) {
    int e = blockIdx.x * 256 + threadIdx.x;
    if (e < Etot) {
        int d = dst[e];
        int pos = rowOff[d] + atomicAdd(&cursor[d], 1);
        srcLst[pos] = src[e];
    }
}

// ---------------- MFMA GEMM (GAT layer): H(bf16) = XS(bf16) @ W ; att dots ----------------

__global__ __launch_bounds__(256) void gemm_att_mfma(
    const unsigned short* __restrict__ XS,
    const unsigned short* __restrict__ WThi, const unsigned short* __restrict__ WTlo,
    const float* __restrict__ attS, const float* __restrict__ attD,
    unsigned short* __restrict__ Hout, float* __restrict__ aSrcP, float* __restrict__ aDstP)
{
    __shared__ __align__(16) unsigned short sCus[64 * PADK];
    __shared__ float sAs[128], sAd[128];
    __shared__ float sPart[64 * 8];

    int tid = threadIdx.x;
    int g0 = blockIdx.x * 64;
    int w = tid >> 6, lane = tid & 63;
    int quad = lane >> 4, mcol = lane & 15;

    if (tid < 128) { sAs[tid] = attS[tid]; sAd[tid] = attD[tid]; }

    float4v acc[4][2];
#pragma unroll
    for (int mt = 0; mt < 4; mt++)
#pragma unroll
        for (int nt = 0; nt < 2; nt++) acc[mt][nt] = (float4v){0.f, 0.f, 0.f, 0.f};

#pragma unroll 1
    for (int term = 0; term < 2; term++) {
        const unsigned short* WT = term ? WTlo : WThi;
        short8 Bf[4][2];
#pragma unroll
        for (int kc = 0; kc < 4; kc++)
#pragma unroll
            for (int nt = 0; nt < 2; nt++)
                Bf[kc][nt] = *(const short8*)(WT + (w * 32 + nt * 16 + mcol) * 128 + kc * 32 + quad * 8);
#pragma unroll
        for (int kc = 0; kc < 4; kc++) {
            short8 Aa[4];
#pragma unroll
            for (int mt = 0; mt < 4; mt++)
                Aa[mt] = *(const short8*)(XS + (size_t)(g0 + mt * 16 + mcol) * 128 + kc * 32 + quad * 8);
#pragma unroll
            for (int mt = 0; mt < 4; mt++)
#pragma unroll
                for (int nt = 0; nt < 2; nt++)
                    acc[mt][nt] = __builtin_amdgcn_mfma_f32_16x16x32_bf16(Aa[mt], Bf[kc][nt], acc[mt][nt], 0, 0, 0);
        }
    }

    __syncthreads();   // sAs/sAd visible

    float pp[16], pd[16];
#pragma unroll
    for (int r16 = 0; r16 < 16; r16++) { pp[r16] = 0.f; pd[r16] = 0.f; }
#pragma unroll
    for (int mt = 0; mt < 4; mt++)
#pragma unroll
        for (int nt = 0; nt < 2; nt++)
#pragma unroll
            for (int reg = 0; reg < 4; reg++) {
                int row = mt * 16 + quad * 4 + reg;   // C/D: col=lane&15, row=quad*4+reg
                int col = w * 32 + nt * 16 + mcol;
                float v = acc[mt][nt][reg];
                sCus[row * PADK + col] = f2bf(v);
                pp[mt * 4 + reg] += v * sAs[col];
                pd[mt * 4 + reg] += v * sAd[col];
            }
#pragma unroll
    for (int off = 1; off < 16; off <<= 1)
#pragma unroll
        for (int r16 = 0; r16 < 16; r16++) {
            pp[r16] += __shfl_xor(pp[r16], off);
            pd[r16] += __shfl_xor(pd[r16], off);
        }
    if (mcol == 0) {
#pragma unroll
        for (int r16 = 0; r16 < 16; r16++) {
            int row = (r16 >> 2) * 16 + quad * 4 + (r16 & 3);
            sPart[row * 8 + w * 2 + 0] = pp[r16];
            sPart[row * 8 + w * 2 + 1] = pd[r16];
        }
    }
    __syncthreads();

    for (int i = tid; i < 64 * 16; i += 256) {
        int r = i >> 4, c8 = i & 15;
        uint4 u = *(uint4*)(sCus + r * PADK + c8 * 8);
        *(uint4*)(Hout + (size_t)(g0 + r) * 128 + c8 * 8) = u;
    }
    if (tid < 64) {
        float s0 = sPart[tid * 8] + sPart[tid * 8 + 2] + sPart[tid * 8 + 4] + sPart[tid * 8 + 6];
        float s1 = sPart[tid * 8 + 1] + sPart[tid * 8 + 3] + sPart[tid * 8 + 5] + sPart[tid * 8 + 7];
        aSrcP[g0 + tid] = s0;
        aDstP[g0 + tid] = s1;
    }
}

// ---------------- fused softmax + aggregate (+ next-layer Wns/bns), bf16 in/out ----------------
// grid (N/4, B): wave w handles node bx*4+w, batch = blockIdx.y. Per-wave LDS, zero barriers.
// Batch-major H: per-batch working set 2.56 MB -> fits per-XCD L2 (x-major dispatch order
// gives temporal batch locality; if interleaved, worst case = old behavior, still correct).

__global__ __launch_bounds__(256) void sm_agg_kernel(
    const int* __restrict__ rowOff, const int* __restrict__ srcLst,
    const float* __restrict__ aSrcP, const float* __restrict__ aDstP,
    const unsigned short* __restrict__ H,
    const float* __restrict__ bias,
    const float* __restrict__ state, const float* __restrict__ wnsN,
    const float* __restrict__ bnsN, int addNext,
    unsigned short* __restrict__ Xout)
{
    __shared__ int   sSrcB[4 * 64];
    __shared__ float sAeB[4 * 64];
    int tid = threadIdx.x;
    int w = tid >> 6, t = tid & 63;
    int n = blockIdx.x * 4 + w;
    int b = blockIdx.y;
    int gb = b * N_NODES;
    int start = rowOff[n], end = rowOff[n + 1];
    int cnt = end - start;
    float adst = aDstP[gb + n];
    int*   sSrc = sSrcB + w * 64;
    float* sAe  = sAeB + w * 64;
    const uint4* H4 = (const uint4*)H;   // 16 uint4 per 128-bf16 row

    if (cnt <= 64) {
        float ae = -1e30f;
        if (t < cnt) {
            int sn = srcLst[start + t];
            sSrc[t] = sn;
            float v = aSrcP[gb + sn] + adst;
            ae = v > 0.f ? v : SLOPE * v;
        }
        float m = ae;
        m = fmaxf(m, __shfl_xor(m, 1));  m = fmaxf(m, __shfl_xor(m, 2));
        m = fmaxf(m, __shfl_xor(m, 4));  m = fmaxf(m, __shfl_xor(m, 8));
        m = fmaxf(m, __shfl_xor(m, 16)); m = fmaxf(m, __shfl_xor(m, 32));
        float e = (t < cnt) ? __expf(ae - m) : 0.f;
        float s = e;
        s += __shfl_xor(s, 1);  s += __shfl_xor(s, 2);  s += __shfl_xor(s, 4);
        s += __shfl_xor(s, 8);  s += __shfl_xor(s, 16); s += __shfl_xor(s, 32);
        float inv = 1.f / s;
        if (t < cnt) sAe[t] = e * inv;
        int cntE = (cnt + 3) & ~3;
        if (t >= cnt && t < cntE) { sSrc[t] = n; sAe[t] = 0.f; }  // zero-alpha pad

        int esub = t >> 4, c16 = t & 15;
        float a0 = 0.f, a1 = 0.f, a2 = 0.f, a3 = 0.f, a4 = 0.f, a5 = 0.f, a6 = 0.f, a7 = 0.f;
        int j = 0;
        for (; j + 16 <= cntE; j += 16) {
            uint4 h[4]; float al[4];
#pragma unroll
            for (int r = 0; r < 4; r++) {
                int jj = j + r * 4 + esub;
                h[r] = H4[(size_t)(gb + sSrc[jj]) * 16 + c16];
                al[r] = sAe[jj];
            }
#pragma unroll
            for (int r = 0; r < 4; r++) {
                a0 += al[r] * bflo(h[r].x); a1 += al[r] * bfhi(h[r].x);
                a2 += al[r] * bflo(h[r].y); a3 += al[r] * bfhi(h[r].y);
                a4 += al[r] * bflo(h[r].z); a5 += al[r] * bfhi(h[r].z);
                a6 += al[r] * bflo(h[r].w); a7 += al[r] * bfhi(h[r].w);
            }
        }
        for (; j < cntE; j += 4) {
            int jj = j + esub;
            uint4 hv = H4[(size_t)(gb + sSrc[jj]) * 16 + c16];
            float al = sAe[jj];
            a0 += al * bflo(hv.x); a1 += al * bfhi(hv.x);
            a2 += al * bflo(hv.y); a3 += al * bfhi(hv.y);
            a4 += al * bflo(hv.z); a5 += al * bfhi(hv.z);
            a6 += al * bflo(hv.w); a7 += al * bfhi(hv.w);
        }
        a0 += __shfl_xor(a0, 16); a1 += __shfl_xor(a1, 16);
        a2 += __shfl_xor(a2, 16); a3 += __shfl_xor(a3, 16);
        a4 += __shfl_xor(a4, 16); a5 += __shfl_xor(a5, 16);
        a6 += __shfl_xor(a6, 16); a7 += __shfl_xor(a7, 16);
        a0 += __shfl_xor(a0, 32); a1 += __shfl_xor(a1, 32);
        a2 += __shfl_xor(a2, 32); a3 += __shfl_xor(a3, 32);
        a4 += __shfl_xor(a4, 32); a5 += __shfl_xor(a5, 32);
        a6 += __shfl_xor(a6, 32); a7 += __shfl_xor(a7, 32);
        if (esub == 0) {
            int d0 = c16 * 8;
            float o0 = fmaxf(a0 + bias[d0],     0.f);
            float o1 = fmaxf(a1 + bias[d0 + 1], 0.f);
            float o2 = fmaxf(a2 + bias[d0 + 2], 0.f);
            float o3 = fmaxf(a3 + bias[d0 + 3], 0.f);
            float o4 = fmaxf(a4 + bias[d0 + 4], 0.f);
            float o5 = fmaxf(a5 + bias[d0 + 5], 0.f);
            float o6 = fmaxf(a6 + bias[d0 + 6], 0.f);
            float o7 = fmaxf(a7 + bias[d0 + 7], 0.f);
            if (addNext) {
                float st = state[gb + n];
                o0 += st * wnsN[d0]     + bnsN[d0];
                o1 += st * wnsN[d0 + 1] + bnsN[d0 + 1];
                o2 += st * wnsN[d0 + 2] + bnsN[d0 + 2];
                o3 += st * wnsN[d0 + 3] + bnsN[d0 + 3];
                o4 += st * wnsN[d0 + 4] + bnsN[d0 + 4];
                o5 += st * wnsN[d0 + 5] + bnsN[d0 + 5];
                o6 += st * wnsN[d0 + 6] + bnsN[d0 + 6];
                o7 += st * wnsN[d0 + 7] + bnsN[d0 + 7];
            }
            uint4 u;
            u.x = (unsigned)f2bf(o0) | ((unsigned)f2bf(o1) << 16);
            u.y = (unsigned)f2bf(o2) | ((unsigned)f2bf(o3) << 16);
            u.z = (unsigned)f2bf(o4) | ((unsigned)f2bf(o5) << 16);
            u.w = (unsigned)f2bf(o6) | ((unsigned)f2bf(o7) << 16);
            ((uint4*)Xout)[(size_t)(gb + n) * 16 + c16] = u;
        }
    } else {
        // fallback (deg > 64, rare) — per-wave LDS, no barriers needed
        const unsigned* Hu = (const unsigned*)H;
        float m = -1e30f;
        for (int i = start + t; i < end; i += 64) {
            int sn = srcLst[i];
            float v = aSrcP[gb + sn] + adst;
            m = fmaxf(m, v > 0.f ? v : SLOPE * v);
        }
        m = fmaxf(m, __shfl_xor(m, 1));  m = fmaxf(m, __shfl_xor(m, 2));
        m = fmaxf(m, __shfl_xor(m, 4));  m = fmaxf(m, __shfl_xor(m, 8));
        m = fmaxf(m, __shfl_xor(m, 16)); m = fmaxf(m, __shfl_xor(m, 32));
        float s = 0.f;
        for (int i = start + t; i < end; i += 64) {
            int sn = srcLst[i];
            float v = aSrcP[gb + sn] + adst;
            float ae2 = v > 0.f ? v : SLOPE * v;
            s += __expf(ae2 - m);
        }
        s += __shfl_xor(s, 1);  s += __shfl_xor(s, 2);  s += __shfl_xor(s, 4);
        s += __shfl_xor(s, 8);  s += __shfl_xor(s, 16); s += __shfl_xor(s, 32);
        float inv = 1.f / s;
        float accx = 0.f, accy = 0.f;
        for (int c0 = start; c0 < end; c0 += 64) {
            int c = min(64, end - c0);
            if (t < c) {
                int sn = srcLst[c0 + t];
                sSrc[t] = sn;
                float v = aSrcP[gb + sn] + adst;
                float ae2 = v > 0.f ? v : SLOPE * v;
                sAe[t] = __expf(ae2 - m);
            }
            for (int j = 0; j < c; j++) {
                float a0 = sAe[j];
                unsigned h0 = Hu[(size_t)(gb + sSrc[j]) * 64 + t];
                accx += a0 * bflo(h0);
                accy += a0 * bfhi(h0);
            }
        }
        float ox = fmaxf(accx * inv + bias[2 * t], 0.f);
        float oy = fmaxf(accy * inv + bias[2 * t + 1], 0.f);
        if (addNext) {
            float st = state[gb + n];
            ox += st * wnsN[2 * t]     + bnsN[2 * t];
            oy += st * wnsN[2 * t + 1] + bnsN[2 * t + 1];
        }
        ((unsigned*)Xout)[(size_t)(gb + n) * 64 + t] =
            (unsigned)f2bf(ox) | ((unsigned)f2bf(oy) << 16);
    }
}

// ---------------- head ----------------

__global__ __launch_bounds__(128) void sum_nodes_kernel(const unsigned short* __restrict__ X, float* state_emb) {
    int cx = blockIdx.x, b = blockIdx.y, d = threadIdx.x;
    int n0 = cx * 157, n1 = n0 + 157;
    if (n1 > N_NODES) n1 = N_NODES;
    float acc = 0.f;
    for (int n = n0; n < n1; n++) acc += bf2f(X[(size_t)(b * N_NODES + n) * 128 + d]);
    atomicAdd(&state_emb[b * 128 + d], acc);
}

// ---------------- final: out = relu(X3@W2+b2).W3[128:] + c1[b] + b3 ; c1 inline ----------------

__global__ __launch_bounds__(256) void final_mfma(
    const unsigned short* __restrict__ X,
    const unsigned short* __restrict__ WThi, const unsigned short* __restrict__ WTlo,
    const float* __restrict__ b2, const float* __restrict__ W3,
    const float* __restrict__ b3,
    const float* __restrict__ state_emb, const float* __restrict__ W1,
    const float* __restrict__ b1,
    float* __restrict__ out)
{
    __shared__ float sB2[128], sW3[128];
    __shared__ float sPart[64 * 4];
    __shared__ float sC1p[8], sC1[4];

    int tid = threadIdx.x;
    int g0 = blockIdx.x * 64;
    int w = tid >> 6, lane = tid & 63;
    int quad = lane >> 4, mcol = lane & 15;

    if (tid < 128) { sB2[tid] = b2[tid]; sW3[tid] = W3[128 + tid]; }

    {
        int d = tid & 127;
        int bh = tid >> 7;   // half 0: b={0,2}; half 1: b={1,3}
        float p0 = b1[d], p1 = b1[d];
        for (int k = 0; k < 128; k++) {
            float wv = W1[k * 128 + d];
            p0 += state_emb[bh * 128 + k] * wv;
            p1 += state_emb[(bh + 2) * 128 + k] * wv;
        }
        float w3d = W3[d];
        p0 = fmaxf(p0, 0.f) * w3d;
        p1 = fmaxf(p1, 0.f) * w3d;
#pragma unroll
        for (int off = 1; off < 64; off <<= 1) {
            p0 += __shfl_xor(p0, off);
            p1 += __shfl_xor(p1, off);
        }
        if (lane == 0) { sC1p[w * 2 + 0] = p0; sC1p[w * 2 + 1] = p1; }
    }
    __syncthreads();
    if (tid == 0) {
        sC1[0] = sC1p[0] + sC1p[2];  sC1[2] = sC1p[1] + sC1p[3];
        sC1[1] = sC1p[4] + sC1p[6];  sC1[3] = sC1p[5] + sC1p[7];
    }

    float4v acc[4][2];
#pragma unroll
    for (int mt = 0; mt < 4; mt++)
#pragma unroll
        for (int nt = 0; nt < 2; nt++) acc[mt][nt] = (float4v){0.f, 0.f, 0.f, 0.f};

#pragma unroll 1
    for (int term = 0; term < 2; term++) {
        const unsigned short* WT = term ? WTlo : WThi;
        short8 Bf[4][2];
#pragma unroll
        for (int kc = 0; kc < 4; kc++)
#pragma unroll
            for (int nt = 0; nt < 2; nt++)
                Bf[kc][nt] = *(const short8*)(WT + (w * 32 + nt * 16 + mcol) * 128 + kc * 32 + quad * 8);
#pragma unroll
        for (int kc = 0; kc < 4; kc++) {
            short8 Aa[4];
#pragma unroll
            for (int mt = 0; mt < 4; mt++)
                Aa[mt] = *(const short8*)(X + (size_t)(g0 + mt * 16 + mcol) * 128 + kc * 32 + quad * 8);
#pragma unroll
            for (int mt = 0; mt < 4; mt++)
#pragma unroll
                for (int nt = 0; nt < 2; nt++)
                    acc[mt][nt] = __builtin_amdgcn_mfma_f32_16x16x32_bf16(Aa[mt], Bf[kc][nt], acc[mt][nt], 0, 0, 0);
        }
    }

    float pp[16];
#pragma unroll
    for (int r16 = 0; r16 < 16; r16++) pp[r16] = 0.f;
#pragma unroll
    for (int mt = 0; mt < 4; mt++)
#pragma unroll
        for (int nt = 0; nt < 2; nt++)
#pragma unroll
            for (int reg = 0; reg < 4; reg++) {
                int col = w * 32 + nt * 16 + mcol;
                float v = acc[mt][nt][reg] + sB2[col];
                v = v > 0.f ? v : 0.f;
                pp[mt * 4 + reg] += v * sW3[col];
            }
#pragma unroll
    for (int off = 1; off < 16; off <<= 1)
#pragma unroll
        for (int r16 = 0; r16 < 16; r16++)
            pp[r16] += __shfl_xor(pp[r16], off);
    if (mcol == 0) {
#pragma unroll
        for (int r16 = 0; r16 < 16; r16++) {
            int row = (r16 >> 2) * 16 + quad * 4 + (r16 & 3);
            sPart[row * 4 + w] = pp[r16];
        }
    }
    __syncthreads();
    if (tid < 64) {
        float p = sPart[tid * 4] + sPart[tid * 4 + 1] + sPart[tid * 4 + 2] + sPart[tid * 4 + 3];
        int g = g0 + tid;
        int b = g / N_NODES;
        out[g] = p + sC1[b] + b3[0];   // batch-major: out index == g
    }
}

// ---------------- launch ----------------

extern "C" void kernel_launch(void* const* d_in, const int* in_sizes, int n_in,
                              void* d_out, int out_size, void* d_ws, size_t ws_size,
                              hipStream_t stream) {
    const float* state    = (const float*)d_in[0];   // [B,N]
    const float* strucEmb = (const float*)d_in[1];   // [N,128]
    const int*   edge_idx = (const int*)d_in[2];     // [2,Etot]
    const float* gat_W    = (const float*)d_in[3];   // [3,128,128]
    const float* gat_aS   = (const float*)d_in[4];
    const float* gat_aD   = (const float*)d_in[5];
    const float* gat_Wns  = (const float*)d_in[6];
    const float* gat_bns  = (const float*)d_in[7];
    const float* gat_bias = (const float*)d_in[8];
    const float* W1 = (const float*)d_in[9];
    const float* b1 = (const float*)d_in[10];
    const float* W2 = (const float*)d_in[11];
    const float* b2 = (const float*)d_in[12];
    const float* W3 = (const float*)d_in[13];
    const float* b3 = (const float*)d_in[14];
    float* out = (float*)d_out;

    int Etot = in_sizes[2] / 2;
    const int* srcArr = edge_idx;
    const int* dstArr = edge_idx + Etot;

    float* ws = (float*)d_ws;
    unsigned short* Xb = (unsigned short*)ws;              // 5,120,000 us
    unsigned short* Hb = (unsigned short*)(ws + 2560000);  // 5,120,000 us
    float* aSrcP       = ws + 5120000;                     // 40,000 f
    float* aDstP       = ws + 5160000;                     // 40,000 f
    float* state_emb   = ws + 5200000;                     // 512 f
    unsigned short* whi = (unsigned short*)(ws + 5200516); // 65,536 us
    unsigned short* wlo = whi + 4 * 16384;                 // 65,536 us
    int*   iws         = (int*)(ws + 5200516 + 65536);
    int*   rowOff      = iws;                              // N+1
    int*   deg         = iws + 10001;
    int*   cursor      = deg + 10000;
    int*   srcLst      = cursor + 10000;                   // Etot

    setup_kernel<<<20296, 256, 0, stream>>>(strucEmb, state, gat_Wns, gat_bns,
                                            gat_W, W2, Xb, whi, wlo, deg, cursor, state_emb);
    hist_kernel<<<(Etot + 255) / 256, 256, 0, stream>>>(dstArr, Etot, deg);
    scan_kernel<<<1, 1024, 0, stream>>>(deg, rowOff);
    scatter_kernel<<<(Etot + 255) / 256, 256, 0, stream>>>(srcArr, dstArr, Etot, rowOff, cursor, srcLst);

    for (int l = 0; l < 3; l++) {
        gemm_att_mfma<<<BN / 64, 256, 0, stream>>>(
            Xb, whi + (size_t)l * 16384, wlo + (size_t)l * 16384,
            gat_aS + l * 128, gat_aD + l * 128, Hb, aSrcP, aDstP);
        sm_agg_kernel<<<dim3(N_NODES / 4, B_SZ), 256, 0, stream>>>(
            rowOff, srcLst, aSrcP, aDstP, Hb, gat_bias + l * 128,
            state, gat_Wns + (l + 1 < 3 ? (l + 1) * 128 : 0),
            gat_bns + (l + 1 < 3 ? (l + 1) * 128 : 0), (l < 2) ? 1 : 0, Xb);
    }

    sum_nodes_kernel<<<dim3(64, B_SZ), 128, 0, stream>>>(Xb, state_emb);
    final_mfma<<<BN / 64, 256, 0, stream>>>(Xb, whi + 3 * 16384, wlo + 3 * 16384,
                                            b2, W3, b3, state_emb, W1, b1, out);
}